// Round 2
// baseline (7491.354 us; speedup 1.0000x reference)
//
#include <hip/hip_runtime.h>
#include <math.h>

#define S_ 2048
#define B_ 2
#define H_ 16
#define E_ 2048
#define QR_ 1536
#define NOPE_ 128
#define ROPE_ 64
#define C_ 512
#define VH_ 128
#define T_ 1024
#define LN1E4 9.210340371976184f

// ---------------- generic fp32 GEMM: C = A @ B or A @ B^T (+bias), batched via grid.z ----
template<bool TRANS_B, bool BIAS>
__global__ __launch_bounds__(256) void gemm_f32(
    const float* __restrict__ A, const float* __restrict__ Bm,
    const float* __restrict__ bias, float* __restrict__ Cm,
    int M, int N, int K, int lda, int ldb, int ldc,
    long sA, long sB, long sC)
{
  A  += (size_t)blockIdx.z * (size_t)sA;
  Bm += (size_t)blockIdx.z * (size_t)sB;
  Cm += (size_t)blockIdx.z * (size_t)sC;
  __shared__ float As[8][132];
  __shared__ float Bs[8][132];
  const int bm = blockIdx.y * 128, bn = blockIdx.x * 128;
  const int tid = threadIdx.x;
  const int tx = tid & 15, ty = tid >> 4;
  float acc[8][8] = {};
  for (int k0 = 0; k0 < K; k0 += 8) {
    {
      int r = tid >> 1, kk = (tid & 1) * 4;
      int gr = bm + r;
      float4 v = make_float4(0.f, 0.f, 0.f, 0.f);
      if (gr < M) v = *(const float4*)(A + (size_t)gr * lda + k0 + kk);
      As[kk + 0][r] = v.x; As[kk + 1][r] = v.y; As[kk + 2][r] = v.z; As[kk + 3][r] = v.w;
    }
    if (TRANS_B) {
      int r = tid >> 1, kk = (tid & 1) * 4;
      int gc = bn + r;
      float4 v = make_float4(0.f, 0.f, 0.f, 0.f);
      if (gc < N) v = *(const float4*)(Bm + (size_t)gc * ldb + k0 + kk);
      Bs[kk + 0][r] = v.x; Bs[kk + 1][r] = v.y; Bs[kk + 2][r] = v.z; Bs[kk + 3][r] = v.w;
    } else {
      int n = tid & 127, kq = tid >> 7;
      int gn = bn + n;
      #pragma unroll
      for (int kk = kq; kk < 8; kk += 2)
        Bs[kk][n] = (gn < N) ? Bm[(size_t)(k0 + kk) * ldb + gn] : 0.f;
    }
    __syncthreads();
    #pragma unroll
    for (int k = 0; k < 8; ++k) {
      float4 a0 = *(const float4*)&As[k][ty * 8];
      float4 a1 = *(const float4*)&As[k][ty * 8 + 4];
      float4 b0 = *(const float4*)&Bs[k][tx * 8];
      float4 b1 = *(const float4*)&Bs[k][tx * 8 + 4];
      float av[8] = {a0.x, a0.y, a0.z, a0.w, a1.x, a1.y, a1.z, a1.w};
      float bv[8] = {b0.x, b0.y, b0.z, b0.w, b1.x, b1.y, b1.z, b1.w};
      #pragma unroll
      for (int i = 0; i < 8; ++i)
        #pragma unroll
        for (int j = 0; j < 8; ++j)
          acc[i][j] = fmaf(av[i], bv[j], acc[i][j]);
    }
    __syncthreads();
  }
  #pragma unroll
  for (int i = 0; i < 8; ++i) {
    int row = bm + ty * 8 + i;
    if (row >= M) continue;
    #pragma unroll
    for (int j = 0; j < 8; ++j) {
      int col = bn + tx * 8 + j;
      if (col < N) {
        float v = acc[i][j];
        if (BIAS) v += bias[col];
        Cm[(size_t)row * ldc + col] = v;
      }
    }
  }
}

// ---------------- row LayerNorm ----------------
__global__ __launch_bounds__(256) void ln_rows(
    const float* __restrict__ in, float* __restrict__ out,
    const float* __restrict__ g, const float* __restrict__ bb,
    int L, int ldin, int ldout)
{
  const int row = blockIdx.x;
  const float* x = in + (size_t)row * ldin;
  float s = 0.f, s2 = 0.f;
  for (int i = threadIdx.x; i < L; i += 256) {
    float v = x[i]; s += v; s2 += v * v;
  }
  #pragma unroll
  for (int off = 32; off; off >>= 1) {
    s  += __shfl_xor(s, off, 64);
    s2 += __shfl_xor(s2, off, 64);
  }
  __shared__ float rs[4], rs2[4];
  int lane = threadIdx.x & 63, w = threadIdx.x >> 6;
  if (lane == 0) { rs[w] = s; rs2[w] = s2; }
  __syncthreads();
  s  = rs[0] + rs[1] + rs[2] + rs[3];
  s2 = rs2[0] + rs2[1] + rs2[2] + rs2[3];
  float mean = s / L;
  float var = s2 / L - mean * mean;
  float inv = rsqrtf(var + 1e-5f);
  float* o = out + (size_t)row * ldout;
  for (int i = threadIdx.x; i < L; i += 256)
    o[i] = (x[i] - mean) * inv * g[i] + bb[i];
}

// ---------------- rope + normalize q_pe (in place in qbuf) ----------------
__global__ __launch_bounds__(64) void rope_norm_q(float* __restrict__ qbuf)
{
  const int idx = blockIdx.x;
  const int h = idx & (H_ - 1);
  const int row = idx >> 4;
  const int s = row & (S_ - 1);
  float* p = qbuf + (size_t)row * (H_ * 192) + h * 192 + NOPE_;
  const int j = threadIdx.x;
  float o1 = 0.f, o2 = 0.f;
  if (j < 32) {
    float invf = expf(-(float)j * (LN1E4 / 32.f));
    float ang = (float)(S_ - 1 + s) * invf;
    float sn, cs; sincosf(ang, &sn, &cs);
    float x1 = p[2 * j], x2 = p[2 * j + 1];
    o1 = x1 * cs - x2 * sn;
    o2 = x1 * sn + x2 * cs;
  }
  float ss = o1 * o1 + o2 * o2;
  #pragma unroll
  for (int off = 32; off; off >>= 1) ss += __shfl_xor(ss, off, 64);
  float nrm = fmaxf(sqrtf(ss), 1e-12f);
  if (j < 32) { p[2 * j] = o1 / nrm; p[2 * j + 1] = o2 / nrm; }
}

// ---------------- rope + normalize k_pe at odd rows only -> kpe_n[b][t][64] ----------------
__global__ __launch_bounds__(64) void rope_norm_k(
    const float* __restrict__ kvf, float* __restrict__ kpe_n)
{
  const int t = blockIdx.x, b = blockIdx.y;
  const int srow = 2 * t + 1;
  const float* p = kvf + ((size_t)(b * S_ + srow)) * 576 + C_;
  const int j = threadIdx.x;
  float o1 = 0.f, o2 = 0.f;
  if (j < 32) {
    float invf = expf(-(float)j * (LN1E4 / 32.f));
    float ang = (float)(S_ - 1 + srow) * invf;
    float sn, cs; sincosf(ang, &sn, &cs);
    float x1 = p[2 * j], x2 = p[2 * j + 1];
    o1 = x1 * cs - x2 * sn;
    o2 = x1 * sn + x2 * cs;
  }
  float ss = o1 * o1 + o2 * o2;
  #pragma unroll
  for (int off = 32; off; off >>= 1) ss += __shfl_xor(ss, off, 64);
  float nrm = fmaxf(sqrtf(ss), 1e-12f);
  if (j < 32) {
    float* o = kpe_n + ((size_t)(b * T_ + t)) * ROPE_;
    o[2 * j] = o1 / nrm; o[2 * j + 1] = o2 / nrm;
  }
}

// ---------------- sinusoidal PE table Cpe[1024][512] ----------------
__global__ __launch_bounds__(256) void pe_kernel(float* __restrict__ Cpe)
{
  const int t = blockIdx.x;
  const int i = threadIdx.x;
  float dv = expf(-(float)(2 * i) * (LN1E4 / 512.f));
  float ang = (float)t * dv;
  float sn, cs; sincosf(ang, &sn, &cs);
  Cpe[(size_t)t * C_ + 2 * i] = sn;
  Cpe[(size_t)t * C_ + 2 * i + 1] = cs;
}

// ---------------- gate: prev_kv[b][t] = w0*kvn[2t] + w1*kvn[2t+1] ----------------
__global__ __launch_bounds__(64) void gate_kernel(
    const float* __restrict__ C2, const float* __restrict__ P2,
    const float* __restrict__ kvn, float* __restrict__ pkv)
{
  const int t = blockIdx.x, b = blockIdx.y;
  const int j = threadIdx.x;
  const float* c2 = C2 + (size_t)t * 128;
  const float* p0 = P2 + ((size_t)(b * S_ + 2 * t)) * 128;
  const float* p1 = p0 + 128;
  float d0 = c2[j] * p0[j] + c2[j + 64] * p0[j + 64];
  float d1 = c2[j] * p1[j] + c2[j + 64] * p1[j + 64];
  #pragma unroll
  for (int off = 32; off; off >>= 1) {
    d0 += __shfl_xor(d0, off, 64);
    d1 += __shfl_xor(d1, off, 64);
  }
  float w0 = 1.f / (1.f + expf(-d0));
  float w1 = 1.f / (1.f + expf(-d1));
  const float* k0 = kvn + ((size_t)(b * S_ + 2 * t)) * C_;
  const float* k1 = k0 + C_;
  float* o = pkv + ((size_t)(b * T_ + t)) * C_;
  for (int c = j * 4; c < C_; c += 256) {
    float4 a = *(const float4*)(k0 + c);
    float4 bb4 = *(const float4*)(k1 + c);
    float4 r;
    r.x = w0 * a.x + w1 * bb4.x;
    r.y = w0 * a.y + w1 * bb4.y;
    r.z = w0 * a.z + w1 * bb4.z;
    r.w = w0 * a.w + w1 * bb4.w;
    *(float4*)(o + c) = r;
  }
}

// ---------------- fused attention: absorption + scores + softmax + PV + out-proj ----------
// 8 q-rows/block. Never materializes qn or x in global memory.
#define QT 8
__global__ __launch_bounds__(256) void attn_fused(
    const float* __restrict__ qbuf, const float* __restrict__ wkvb,
    const float* __restrict__ pkv, const float* __restrict__ kpe,
    const float* __restrict__ ps_ptr, float* __restrict__ x2out)
{
  __shared__ float qn_lds[QT][NOPE_];  // 4 KB
  __shared__ float qs[QT][C_];         // 16 KB (later reused for x)
  __shared__ float qp[QT][ROPE_];      // 2 KB
  __shared__ float sc[QT][T_];         // 32 KB
  const int b = blockIdx.z, h = blockIdx.y, s0 = blockIdx.x * QT;
  const int tid = threadIdx.x;
  const float pos_scale = ps_ptr[0];
  // load q_nope + q_pe (pos_scale folded into q_pe)
  for (int i = tid; i < QT * NOPE_; i += 256) {
    int r = i >> 7, c = i & 127;
    qn_lds[r][c] = qbuf[((size_t)(b * S_ + s0 + r)) * (H_ * 192) + h * 192 + c];
  }
  for (int i = tid; i < QT * ROPE_; i += 256) {
    int r = i >> 6, c = i & 63;
    qp[r][c] = qbuf[((size_t)(b * S_ + s0 + r)) * (H_ * 192) + h * 192 + NOPE_ + c] * pos_scale;
  }
  __syncthreads();
  // absorption: qs[r][c] = sum_k qn_lds[r][k] * wkvb[h][k][c]
  {
    const float* W1 = wkvb + (size_t)h * 256 * C_;
    const int c0 = tid * 2;
    float a0[QT] = {}, a1[QT] = {};
    for (int k = 0; k < NOPE_; ++k) {
      float2 wv = *(const float2*)(W1 + (size_t)k * C_ + c0);
      #pragma unroll
      for (int r = 0; r < QT; ++r) {
        a0[r] = fmaf(qn_lds[r][k], wv.x, a0[r]);
        a1[r] = fmaf(qn_lds[r][k], wv.y, a1[r]);
      }
    }
    #pragma unroll
    for (int r = 0; r < QT; ++r) { qs[r][c0] = a0[r]; qs[r][c0 + 1] = a1[r]; }
  }
  __syncthreads();
  const float scale = 0.07216878364870323f; // 192^-0.5
  // pass 1: scores
  {
    const float* kvb = pkv + (size_t)b * T_ * C_;
    const float* kpb = kpe + (size_t)b * T_ * ROPE_;
    float acc[4][QT] = {};
    for (int c = 0; c < C_; c += 4) {
      float4 v0 = *(const float4*)(kvb + (size_t)(tid)       * C_ + c);
      float4 v1 = *(const float4*)(kvb + (size_t)(tid + 256) * C_ + c);
      float4 v2 = *(const float4*)(kvb + (size_t)(tid + 512) * C_ + c);
      float4 v3 = *(const float4*)(kvb + (size_t)(tid + 768) * C_ + c);
      #pragma unroll
      for (int r = 0; r < QT; ++r) {
        float4 q = *(const float4*)&qs[r][c];
        acc[0][r] += q.x * v0.x + q.y * v0.y + q.z * v0.z + q.w * v0.w;
        acc[1][r] += q.x * v1.x + q.y * v1.y + q.z * v1.z + q.w * v1.w;
        acc[2][r] += q.x * v2.x + q.y * v2.y + q.z * v2.z + q.w * v2.w;
        acc[3][r] += q.x * v3.x + q.y * v3.y + q.z * v3.z + q.w * v3.w;
      }
    }
    for (int c = 0; c < ROPE_; c += 4) {
      float4 v0 = *(const float4*)(kpb + (size_t)(tid)       * ROPE_ + c);
      float4 v1 = *(const float4*)(kpb + (size_t)(tid + 256) * ROPE_ + c);
      float4 v2 = *(const float4*)(kpb + (size_t)(tid + 512) * ROPE_ + c);
      float4 v3 = *(const float4*)(kpb + (size_t)(tid + 768) * ROPE_ + c);
      #pragma unroll
      for (int r = 0; r < QT; ++r) {
        float4 q = *(const float4*)&qp[r][c];
        acc[0][r] += q.x * v0.x + q.y * v0.y + q.z * v0.z + q.w * v0.w;
        acc[1][r] += q.x * v1.x + q.y * v1.y + q.z * v1.z + q.w * v1.w;
        acc[2][r] += q.x * v2.x + q.y * v2.y + q.z * v2.z + q.w * v2.w;
        acc[3][r] += q.x * v3.x + q.y * v3.y + q.z * v3.z + q.w * v3.w;
      }
    }
    #pragma unroll
    for (int tb = 0; tb < 4; ++tb)
      #pragma unroll
      for (int r = 0; r < QT; ++r)
        sc[r][tid + tb * 256] = acc[tb][r] * scale;
  }
  __syncthreads();
  // softmax per row over 1024
  {
    const int lane = tid & 63, w = tid >> 6;
    for (int r = w; r < QT; r += 4) {
      float m = -1e30f;
      for (int t = lane; t < T_; t += 64) m = fmaxf(m, sc[r][t]);
      #pragma unroll
      for (int off = 32; off; off >>= 1) m = fmaxf(m, __shfl_xor(m, off, 64));
      float sum = 0.f;
      for (int t = lane; t < T_; t += 64) {
        float e = __expf(sc[r][t] - m);
        sc[r][t] = e; sum += e;
      }
      #pragma unroll
      for (int off = 32; off; off >>= 1) sum += __shfl_xor(sum, off, 64);
      float rinv = 1.f / sum;
      for (int t = lane; t < T_; t += 64) sc[r][t] *= rinv;
    }
  }
  __syncthreads();
  // pass 2: x = P @ prev_kv; thread owns 2 columns; write x into qs (reuse)
  {
    const float* kvb = pkv + (size_t)b * T_ * C_;
    const int c0 = tid * 2;
    float accx[QT] = {}, accy[QT] = {};
    for (int t = 0; t < T_; t += 4) {
      float2 v0 = *(const float2*)(kvb + (size_t)(t + 0) * C_ + c0);
      float2 v1 = *(const float2*)(kvb + (size_t)(t + 1) * C_ + c0);
      float2 v2 = *(const float2*)(kvb + (size_t)(t + 2) * C_ + c0);
      float2 v3 = *(const float2*)(kvb + (size_t)(t + 3) * C_ + c0);
      #pragma unroll
      for (int r = 0; r < QT; ++r) {
        float4 pr = *(const float4*)&sc[r][t];
        accx[r] += pr.x * v0.x + pr.y * v1.x + pr.z * v2.x + pr.w * v3.x;
        accy[r] += pr.x * v0.y + pr.y * v1.y + pr.z * v2.y + pr.w * v3.y;
      }
    }
    __syncthreads(); // pass-1 reads of qs long done; safe to overwrite
    #pragma unroll
    for (int r = 0; r < QT; ++r) { qs[r][c0] = accx[r]; qs[r][c0 + 1] = accy[r]; }
  }
  __syncthreads();
  // out-proj: x2[r][d] = sum_c x[r][c] * wkvb[h][128+d][c]
  {
    const float* W2 = wkvb + (size_t)h * 256 * C_ + (size_t)NOPE_ * C_;
    const int d = tid & 127;
    const int r0 = (tid >> 7) * 4;
    float acc[4] = {};
    for (int c = 0; c < C_; c += 4) {
      float4 wv = *(const float4*)(W2 + (size_t)d * C_ + c);
      #pragma unroll
      for (int j = 0; j < 4; ++j) {
        float4 xv = *(const float4*)&qs[r0 + j][c];
        acc[j] += xv.x * wv.x + xv.y * wv.y + xv.z * wv.z + xv.w * wv.w;
      }
    }
    #pragma unroll
    for (int j = 0; j < 4; ++j)
      x2out[((size_t)(b * S_ + s0 + r0 + j)) * (H_ * VH_) + h * VH_ + d] = acc[j];
  }
}

extern "C" void kernel_launch(void* const* d_in, const int* in_sizes, int n_in,
                              void* d_out, int out_size, void* d_ws, size_t ws_size,
                              hipStream_t stream)
{
  (void)in_sizes; (void)n_in; (void)out_size; (void)ws_size;
  const float* query  = (const float*)d_in[0];
  const float* key    = (const float*)d_in[1];
  const float* wq_a   = (const float*)d_in[3];
  const float* q_ln_g = (const float*)d_in[4];
  const float* q_ln_b = (const float*)d_in[5];
  const float* wq_b   = (const float*)d_in[6];
  const float* wkv_a  = (const float*)d_in[7];
  const float* kv_ln_g= (const float*)d_in[8];
  const float* kv_ln_b= (const float*)d_in[9];
  const float* wkvb   = (const float*)d_in[10];
  const float* wo     = (const float*)d_in[11];
  const float* fc_c_w = (const float*)d_in[12];
  const float* fc_c_b = (const float*)d_in[13];
  const float* fc_p_w = (const float*)d_in[14];
  const float* fc_p_b = (const float*)d_in[15];
  const float* ps     = (const float*)d_in[16];
  float* out = (float*)d_out;

  const int M = B_ * S_; // 4096
  // workspace layout (93.3 MB total; x2 aliases dead kvf/kvn):
  float* w = (float*)d_ws;
  float* qbuf = w;                       // M*3072            = 12,582,912
  float* kpeN = qbuf + (size_t)M * 3072; // B*T*64            =    131,072
  float* Cpe  = kpeN + (size_t)B_ * T_ * ROPE_;   // T*512    =    524,288
  float* C2   = Cpe  + (size_t)T_ * C_;           // T*128    =    131,072
  float* P2   = C2   + (size_t)T_ * 128;          // M*128    =    524,288
  float* pkv  = P2   + (size_t)M * 128;           // B*T*512  =  1,048,576
  float* xreg = pkv  + (size_t)B_ * T_ * C_;      // 8,388,608 (kvf/kvn then x2)
  float* kvf  = xreg;                             // M*576 (dead before x2 write)
  float* kvn  = xreg + (size_t)M * 576;           // M*512 (dead before x2 write)
  float* x2   = xreg;                             // M*2048
  // qlp lives in d_out (dead after step 3; d_out fully rewritten at the end)
  float* qlp  = out;

  // 1. qlp = query @ wq_a^T
  gemm_f32<true,false><<<dim3(QR_/128, M/128, 1), 256, 0, stream>>>(
      query, wq_a, nullptr, qlp, M, QR_, E_, E_, E_, QR_, 0, 0, 0);
  // 2. ql = LN(qlp) in place
  ln_rows<<<M, 256, 0, stream>>>(qlp, qlp, q_ln_g, q_ln_b, QR_, QR_, QR_);
  // 3. qbuf = ql @ wq_b^T
  gemm_f32<true,false><<<dim3((H_*192)/128, M/128, 1), 256, 0, stream>>>(
      qlp, wq_b, nullptr, qbuf, M, H_*192, QR_, QR_, QR_, H_*192, 0, 0, 0);
  // 4. rope + normalize q_pe in place
  rope_norm_q<<<M * H_, 64, 0, stream>>>(qbuf);
  // 5. kvf = key @ wkv_a^T
  gemm_f32<true,false><<<dim3((576 + 127)/128, M/128, 1), 256, 0, stream>>>(
      key, wkv_a, nullptr, kvf, M, 576, E_, E_, E_, 576, 0, 0, 0);
  // 6. kvn = LN(kvf[:, :512])
  ln_rows<<<M, 256, 0, stream>>>(kvf, kvn, kv_ln_g, kv_ln_b, C_, 576, C_);
  // 7. kpe_n (odd rows roped + normalized)
  rope_norm_k<<<dim3(T_, B_), 64, 0, stream>>>(kvf, kpeN);
  // 8. Cpe table
  pe_kernel<<<T_, 256, 0, stream>>>(Cpe);
  // 9. C2 = Cpe @ fc_c_w^T + b
  gemm_f32<true,true><<<dim3(1, T_/128, 1), 256, 0, stream>>>(
      Cpe, fc_c_w, fc_c_b, C2, T_, 128, C_, C_, C_, 128, 0, 0, 0);
  // 10. P2 = kvn @ fc_p_w^T + b
  gemm_f32<true,true><<<dim3(1, M/128, 1), 256, 0, stream>>>(
      kvn, fc_p_w, fc_p_b, P2, M, 128, C_, C_, C_, 128, 0, 0, 0);
  // 11. gated 2-tap temporal pooling -> prev_kv
  gate_kernel<<<dim3(T_, B_), 64, 0, stream>>>(C2, P2, kvn, pkv);
  // 12. fused attention (absorption + scores + softmax + PV + out-proj) -> x2
  //     (x2 overwrites kvf/kvn, both dead now)
  attn_fused<<<dim3(S_/QT, H_, B_), 256, 0, stream>>>(qbuf, wkvb, pkv, kpeN, ps, x2);
  // 13. out = x2 @ wo^T
  gemm_f32<true,false><<<dim3(E_/128, M/128, 1), 256, 0, stream>>>(
      x2, wo, nullptr, out, M, E_, H_*VH_, H_*VH_, H_*VH_, E_, 0, 0, 0);
}

// Round 3
// 3474.541 us; speedup vs baseline: 2.1561x; 2.1561x over previous
//
#include <hip/hip_runtime.h>
#include <math.h>

#define S_ 2048
#define B_ 2
#define H_ 16
#define E_ 2048
#define QR_ 1536
#define NOPE_ 128
#define ROPE_ 64
#define C_ 512
#define VH_ 128
#define T_ 1024
#define LN1E4 9.210340371976184f
#define SCALE_ 0.07216878364870323f  // 192^-0.5

typedef _Float16 half8 __attribute__((ext_vector_type(8)));
typedef float floatx4 __attribute__((ext_vector_type(4)));

// ---------------- generic fp32 GEMM: C = A @ B^T (+bias) ----
template<bool TRANS_B, bool BIAS>
__global__ __launch_bounds__(256) void gemm_f32(
    const float* __restrict__ A, const float* __restrict__ Bm,
    const float* __restrict__ bias, float* __restrict__ Cm,
    int M, int N, int K, int lda, int ldb, int ldc)
{
  __shared__ float As[8][132];
  __shared__ float Bs[8][132];
  const int bm = blockIdx.y * 128, bn = blockIdx.x * 128;
  const int tid = threadIdx.x;
  const int tx = tid & 15, ty = tid >> 4;
  float acc[8][8] = {};
  for (int k0 = 0; k0 < K; k0 += 8) {
    {
      int r = tid >> 1, kk = (tid & 1) * 4;
      int gr = bm + r;
      float4 v = make_float4(0.f, 0.f, 0.f, 0.f);
      if (gr < M) v = *(const float4*)(A + (size_t)gr * lda + k0 + kk);
      As[kk + 0][r] = v.x; As[kk + 1][r] = v.y; As[kk + 2][r] = v.z; As[kk + 3][r] = v.w;
    }
    {
      int r = tid >> 1, kk = (tid & 1) * 4;
      int gc = bn + r;
      float4 v = make_float4(0.f, 0.f, 0.f, 0.f);
      if (gc < N) v = *(const float4*)(Bm + (size_t)gc * ldb + k0 + kk);
      Bs[kk + 0][r] = v.x; Bs[kk + 1][r] = v.y; Bs[kk + 2][r] = v.z; Bs[kk + 3][r] = v.w;
    }
    __syncthreads();
    #pragma unroll
    for (int k = 0; k < 8; ++k) {
      float4 a0 = *(const float4*)&As[k][ty * 8];
      float4 a1 = *(const float4*)&As[k][ty * 8 + 4];
      float4 b0 = *(const float4*)&Bs[k][tx * 8];
      float4 b1 = *(const float4*)&Bs[k][tx * 8 + 4];
      float av[8] = {a0.x, a0.y, a0.z, a0.w, a1.x, a1.y, a1.z, a1.w};
      float bv[8] = {b0.x, b0.y, b0.z, b0.w, b1.x, b1.y, b1.z, b1.w};
      #pragma unroll
      for (int i = 0; i < 8; ++i)
        #pragma unroll
        for (int j = 0; j < 8; ++j)
          acc[i][j] = fmaf(av[i], bv[j], acc[i][j]);
    }
    __syncthreads();
  }
  #pragma unroll
  for (int i = 0; i < 8; ++i) {
    int row = bm + ty * 8 + i;
    if (row >= M) continue;
    #pragma unroll
    for (int j = 0; j < 8; ++j) {
      int col = bn + tx * 8 + j;
      if (col < N) {
        float v = acc[i][j];
        if (BIAS) v += bias[col];
        Cm[(size_t)row * ldc + col] = v;
      }
    }
  }
}

// ---------------- row LayerNorm ----------------
__global__ __launch_bounds__(256) void ln_rows(
    const float* __restrict__ in, float* __restrict__ out,
    const float* __restrict__ g, const float* __restrict__ bb,
    int L, int ldin, int ldout)
{
  const int row = blockIdx.x;
  const float* x = in + (size_t)row * ldin;
  float s = 0.f, s2 = 0.f;
  for (int i = threadIdx.x; i < L; i += 256) {
    float v = x[i]; s += v; s2 += v * v;
  }
  #pragma unroll
  for (int off = 32; off; off >>= 1) {
    s  += __shfl_xor(s, off, 64);
    s2 += __shfl_xor(s2, off, 64);
  }
  __shared__ float rs[4], rs2[4];
  int lane = threadIdx.x & 63, w = threadIdx.x >> 6;
  if (lane == 0) { rs[w] = s; rs2[w] = s2; }
  __syncthreads();
  s  = rs[0] + rs[1] + rs[2] + rs[3];
  s2 = rs2[0] + rs2[1] + rs2[2] + rs2[3];
  float mean = s / L;
  float var = s2 / L - mean * mean;
  float inv = rsqrtf(var + 1e-5f);
  float* o = out + (size_t)row * ldout;
  for (int i = threadIdx.x; i < L; i += 256)
    o[i] = (x[i] - mean) * inv * g[i] + bb[i];
}

// ------- conv_q: rope+normalize q_pe (×ps×scale), convert whole row to f16 in place -------
// f16 row r lives at (half*)qbuf + r*6144, stride 6144 halves.
__global__ __launch_bounds__(256) void conv_q(float* __restrict__ qbuf,
                                              const float* __restrict__ ps_ptr)
{
  __shared__ float row[3072];
  const int r = blockIdx.x;
  const int s = r & (S_ - 1);
  const int tid = threadIdx.x;
  float* src = qbuf + (size_t)r * 3072;
  for (int i = tid; i < 768; i += 256)
    ((float4*)row)[i] = ((const float4*)src)[i];
  __syncthreads();
  const float psc = ps_ptr[0] * SCALE_;
  const int lane = tid & 63, w = tid >> 6;
  for (int h = w; h < 16; h += 4) {
    float o1 = 0.f, o2 = 0.f;
    if (lane < 32) {
      float invf = expf(-(float)lane * (LN1E4 / 32.f));
      float ang = (float)(S_ - 1 + s) * invf;
      float sn, cs; sincosf(ang, &sn, &cs);
      float x1 = row[h * 192 + 128 + 2 * lane], x2 = row[h * 192 + 128 + 2 * lane + 1];
      o1 = x1 * cs - x2 * sn;
      o2 = x1 * sn + x2 * cs;
    }
    float ss = o1 * o1 + o2 * o2;
    #pragma unroll
    for (int off = 32; off; off >>= 1) ss += __shfl_xor(ss, off, 64);
    float inv = psc / fmaxf(sqrtf(ss), 1e-12f);
    if (lane < 32) {
      row[h * 192 + 128 + 2 * lane]     = o1 * inv;
      row[h * 192 + 128 + 2 * lane + 1] = o2 * inv;
    }
  }
  __syncthreads();
  _Float16* dst = (_Float16*)(qbuf + (size_t)r * 3072);
  for (int i = tid; i < 3072; i += 256) dst[i] = (_Float16)row[i];
}

// ---------------- rope + normalize k_pe (odd rows) -> f16 ----------------
__global__ __launch_bounds__(64) void rope_norm_k(
    const float* __restrict__ kvf, _Float16* __restrict__ kpe16)
{
  const int t = blockIdx.x, b = blockIdx.y;
  const int srow = 2 * t + 1;
  const float* p = kvf + ((size_t)(b * S_ + srow)) * 576 + C_;
  const int j = threadIdx.x;
  float o1 = 0.f, o2 = 0.f;
  if (j < 32) {
    float invf = expf(-(float)j * (LN1E4 / 32.f));
    float ang = (float)(S_ - 1 + srow) * invf;
    float sn, cs; sincosf(ang, &sn, &cs);
    float x1 = p[2 * j], x2 = p[2 * j + 1];
    o1 = x1 * cs - x2 * sn;
    o2 = x1 * sn + x2 * cs;
  }
  float ss = o1 * o1 + o2 * o2;
  #pragma unroll
  for (int off = 32; off; off >>= 1) ss += __shfl_xor(ss, off, 64);
  float nrm = fmaxf(sqrtf(ss), 1e-12f);
  if (j < 32) {
    _Float16* o = kpe16 + ((size_t)(b * T_ + t)) * ROPE_;
    o[2 * j] = (_Float16)(o1 / nrm);
    o[2 * j + 1] = (_Float16)(o2 / nrm);
  }
}

// ---------------- sinusoidal PE table ----------------
__global__ __launch_bounds__(256) void pe_kernel(float* __restrict__ Cpe)
{
  const int t = blockIdx.x;
  const int i = threadIdx.x;
  float dv = expf(-(float)(2 * i) * (LN1E4 / 512.f));
  float ang = (float)t * dv;
  float sn, cs; sincosf(ang, &sn, &cs);
  Cpe[(size_t)t * C_ + 2 * i] = sn;
  Cpe[(size_t)t * C_ + 2 * i + 1] = cs;
}

// --------- gate: prev_kv f16 (row-major [t][c] and transposed [c][t]) ----------
__global__ __launch_bounds__(64) void gate_kernel(
    const float* __restrict__ C2, const float* __restrict__ P2,
    const float* __restrict__ kvn, _Float16* __restrict__ pkv16,
    _Float16* __restrict__ pkvT16)
{
  const int t = blockIdx.x, b = blockIdx.y;
  const int j = threadIdx.x;
  const float* c2 = C2 + (size_t)t * 128;
  const float* p0 = P2 + ((size_t)(b * S_ + 2 * t)) * 128;
  const float* p1 = p0 + 128;
  float d0 = c2[j] * p0[j] + c2[j + 64] * p0[j + 64];
  float d1 = c2[j] * p1[j] + c2[j + 64] * p1[j + 64];
  #pragma unroll
  for (int off = 32; off; off >>= 1) {
    d0 += __shfl_xor(d0, off, 64);
    d1 += __shfl_xor(d1, off, 64);
  }
  float w0 = 1.f / (1.f + expf(-d0));
  float w1 = 1.f / (1.f + expf(-d1));
  const float* k0 = kvn + ((size_t)(b * S_ + 2 * t)) * C_;
  const float* k1 = k0 + C_;
  _Float16* o = pkv16 + ((size_t)(b * T_ + t)) * C_;
  _Float16* oT = pkvT16 + (size_t)b * C_ * T_;
  #pragma unroll
  for (int it = 0; it < 2; ++it) {
    int c = j * 4 + it * 256;
    float4 a = *(const float4*)(k0 + c);
    float4 bb = *(const float4*)(k1 + c);
    _Float16 h0 = (_Float16)(w0 * a.x + w1 * bb.x);
    _Float16 h1 = (_Float16)(w0 * a.y + w1 * bb.y);
    _Float16 h2 = (_Float16)(w0 * a.z + w1 * bb.z);
    _Float16 h3 = (_Float16)(w0 * a.w + w1 * bb.w);
    o[c] = h0; o[c + 1] = h1; o[c + 2] = h2; o[c + 3] = h3;
    oT[(size_t)(c + 0) * T_ + t] = h0;
    oT[(size_t)(c + 1) * T_ + t] = h1;
    oT[(size_t)(c + 2) * T_ + t] = h2;
    oT[(size_t)(c + 3) * T_ + t] = h3;
  }
}

// ---- conv_wkvb: W1T[h][c][d] = wkvb[h][d][c]*scale (f16); W2c[h][d][c] = wkvb[h][128+d][c] ----
__global__ __launch_bounds__(256) void conv_wkvb(
    const float* __restrict__ wkvb, _Float16* __restrict__ W1T,
    _Float16* __restrict__ W2c)
{
  int tid = blockIdx.x * 256 + threadIdx.x;
  if (tid < 16 * 512 * 128) {
    int d = tid & 127, c = (tid >> 7) & 511, h = tid >> 16;
    W1T[tid] = (_Float16)(wkvb[((size_t)(h * 256) + d) * 512 + c] * SCALE_);
  } else {
    int i = tid - 16 * 512 * 128;
    int c = i & 511, d = (i >> 9) & 127, h = i >> 16;
    W2c[i] = (_Float16)wkvb[((size_t)(h * 256) + 128 + d) * 512 + c];
  }
}

// ---------------- MFMA flash attention (f16), fully wave-independent ----------------
// Block = 4 waves x 16 q-rows = 64 rows. Per wave: absorb -> K-loop (scores,
// online softmax, PV) -> out-proj. No __syncthreads anywhere.
#define MFMA16(a, b, c) __builtin_amdgcn_mfma_f32_16x16x32_f16(a, b, c, 0, 0, 0)
#define QSLD 520
__global__ __launch_bounds__(256, 2) void attn_mfma(
    const _Float16* __restrict__ qb16, const _Float16* __restrict__ W1T,
    const _Float16* __restrict__ W2c, const _Float16* __restrict__ pkv16,
    const _Float16* __restrict__ pkvT16, const _Float16* __restrict__ kpe16,
    float* __restrict__ x2)
{
  __shared__ __align__(16) _Float16 Qs[64 * QSLD];  // absorbed Q (later reused for x)
  __shared__ __align__(16) _Float16 Pl[64 * 72];    // per-wave P tiles
  const int b = blockIdx.z, h = blockIdx.y, st = blockIdx.x;
  const int tid = threadIdx.x, w = tid >> 6, lane = tid & 63;
  const int l15 = lane & 15, g = lane >> 4;
  const int s0 = st * 64 + w * 16;
  const int rq = b * S_ + s0;

  const _Float16* qrow = qb16 + (size_t)(rq + l15) * 6144 + h * 192;

  // ---- absorption: Qs[q][c] = (q_nope @ W1)[q][c] * scale ----
  {
    floatx4 accq[32];
    #pragma unroll
    for (int i = 0; i < 32; ++i) accq[i] = (floatx4){0.f, 0.f, 0.f, 0.f};
    #pragma unroll
    for (int kk = 0; kk < 4; ++kk) {
      half8 a = *(const half8*)(qrow + kk * 32 + g * 8);
      const _Float16* wp = W1T + ((size_t)h * 512 + l15) * 128 + kk * 32 + g * 8;
      #pragma unroll
      for (int cc = 0; cc < 32; ++cc)
        accq[cc] = MFMA16(a, *(const half8*)(wp + cc * 16 * 128), accq[cc]);
    }
    #pragma unroll
    for (int cc = 0; cc < 32; ++cc)
      #pragma unroll
      for (int r = 0; r < 4; ++r)
        Qs[(w * 16 + g * 4 + r) * QSLD + cc * 16 + l15] = (_Float16)accq[cc][r];
  }
  // qp fragments (pos-scaled at conv_q)
  half8 qpA0 = *(const half8*)(qrow + 128 + g * 8);
  half8 qpA1 = *(const half8*)(qrow + 160 + g * 8);

  floatx4 O[32];
  #pragma unroll
  for (int i = 0; i < 32; ++i) O[i] = (floatx4){0.f, 0.f, 0.f, 0.f};
  float m[4] = {-3e38f, -3e38f, -3e38f, -3e38f};
  float l[4] = {0.f, 0.f, 0.f, 0.f};
  const _Float16* pkvb  = pkv16  + (size_t)b * T_ * C_;
  const _Float16* pkvTb = pkvT16 + (size_t)b * C_ * T_;
  const _Float16* kpeb  = kpe16  + (size_t)b * T_ * ROPE_;

  for (int kt = 0; kt < 16; ++kt) {
    const int t0 = kt * 64;
    floatx4 sc[4];
    #pragma unroll
    for (int i = 0; i < 4; ++i) sc[i] = (floatx4){0.f, 0.f, 0.f, 0.f};
    // scores: content
    #pragma unroll
    for (int kk = 0; kk < 16; ++kk) {
      half8 a = *(const half8*)&Qs[(w * 16 + l15) * QSLD + kk * 32 + g * 8];
      const _Float16* kp = pkvb + (size_t)(t0 + l15) * C_ + kk * 32 + g * 8;
      sc[0] = MFMA16(a, *(const half8*)(kp),            sc[0]);
      sc[1] = MFMA16(a, *(const half8*)(kp + 16 * C_), sc[1]);
      sc[2] = MFMA16(a, *(const half8*)(kp + 32 * C_), sc[2]);
      sc[3] = MFMA16(a, *(const half8*)(kp + 48 * C_), sc[3]);
    }
    // scores: positional
    {
      const _Float16* kp = kpeb + (size_t)(t0 + l15) * ROPE_ + g * 8;
      #pragma unroll
      for (int ct = 0; ct < 4; ++ct) {
        sc[ct] = MFMA16(qpA0, *(const half8*)(kp + ct * 16 * ROPE_),      sc[ct]);
        sc[ct] = MFMA16(qpA1, *(const half8*)(kp + ct * 16 * ROPE_ + 32), sc[ct]);
      }
    }
    // online softmax (rows r live in reg r; reduce across the 16-lane col group)
    float pm[4], sf[4], rs[4];
    #pragma unroll
    for (int r = 0; r < 4; ++r)
      pm[r] = fmaxf(fmaxf(sc[0][r], sc[1][r]), fmaxf(sc[2][r], sc[3][r]));
    #pragma unroll
    for (int off = 1; off < 16; off <<= 1)
      #pragma unroll
      for (int r = 0; r < 4; ++r) pm[r] = fmaxf(pm[r], __shfl_xor(pm[r], off, 64));
    #pragma unroll
    for (int r = 0; r < 4; ++r) {
      float mn = fmaxf(m[r], pm[r]);
      sf[r] = __expf(m[r] - mn);
      m[r] = mn;
      rs[r] = 0.f;
    }
    #pragma unroll
    for (int ct = 0; ct < 4; ++ct)
      #pragma unroll
      for (int r = 0; r < 4; ++r) {
        float e = __expf(sc[ct][r] - m[r]);
        sc[ct][r] = e; rs[r] += e;
      }
    #pragma unroll
    for (int off = 1; off < 16; off <<= 1)
      #pragma unroll
      for (int r = 0; r < 4; ++r) rs[r] += __shfl_xor(rs[r], off, 64);
    #pragma unroll
    for (int r = 0; r < 4; ++r) l[r] = l[r] * sf[r] + rs[r];
    #pragma unroll
    for (int cc = 0; cc < 32; ++cc) {
      O[cc][0] *= sf[0]; O[cc][1] *= sf[1]; O[cc][2] *= sf[2]; O[cc][3] *= sf[3];
    }
    // P -> LDS (D-layout -> A-layout via LDS)
    #pragma unroll
    for (int ct = 0; ct < 4; ++ct)
      #pragma unroll
      for (int r = 0; r < 4; ++r)
        Pl[(w * 16 + g * 4 + r) * 72 + ct * 16 + l15] = (_Float16)sc[ct][r];
    // PV
    #pragma unroll
    for (int kc = 0; kc < 2; ++kc) {
      half8 pa = *(const half8*)&Pl[(w * 16 + l15) * 72 + kc * 32 + g * 8];
      const _Float16* vp = pkvTb + (size_t)l15 * T_ + t0 + kc * 32 + g * 8;
      #pragma unroll
      for (int cc = 0; cc < 32; ++cc)
        O[cc] = MFMA16(pa, *(const half8*)(vp + (size_t)cc * 16 * T_), O[cc]);
    }
  }

  // ---- epilogue: normalize, x -> LDS (reuse Qs, own rows only), out-proj ----
  float il[4] = {1.f / l[0], 1.f / l[1], 1.f / l[2], 1.f / l[3]};
  #pragma unroll
  for (int cc = 0; cc < 32; ++cc)
    #pragma unroll
    for (int r = 0; r < 4; ++r)
      Qs[(w * 16 + g * 4 + r) * QSLD + cc * 16 + l15] = (_Float16)(O[cc][r] * il[r]);
  floatx4 xo[8];
  #pragma unroll
  for (int i = 0; i < 8; ++i) xo[i] = (floatx4){0.f, 0.f, 0.f, 0.f};
  #pragma unroll
  for (int kk = 0; kk < 16; ++kk) {
    half8 a = *(const half8*)&Qs[(w * 16 + l15) * QSLD + kk * 32 + g * 8];
    const _Float16* wp = W2c + ((size_t)h * 128 + l15) * 512 + kk * 32 + g * 8;
    #pragma unroll
    for (int dd = 0; dd < 8; ++dd)
      xo[dd] = MFMA16(a, *(const half8*)(wp + dd * 16 * 512), xo[dd]);
  }
  #pragma unroll
  for (int dd = 0; dd < 8; ++dd)
    #pragma unroll
    for (int r = 0; r < 4; ++r)
      x2[(size_t)(rq + g * 4 + r) * 2048 + h * 128 + dd * 16 + l15] = xo[dd][r];
}

extern "C" void kernel_launch(void* const* d_in, const int* in_sizes, int n_in,
                              void* d_out, int out_size, void* d_ws, size_t ws_size,
                              hipStream_t stream)
{
  (void)in_sizes; (void)n_in; (void)out_size; (void)ws_size;
  const float* query  = (const float*)d_in[0];
  const float* key    = (const float*)d_in[1];
  const float* wq_a   = (const float*)d_in[3];
  const float* q_ln_g = (const float*)d_in[4];
  const float* q_ln_b = (const float*)d_in[5];
  const float* wq_b   = (const float*)d_in[6];
  const float* wkv_a  = (const float*)d_in[7];
  const float* kv_ln_g= (const float*)d_in[8];
  const float* kv_ln_b= (const float*)d_in[9];
  const float* wkvb   = (const float*)d_in[10];
  const float* wo     = (const float*)d_in[11];
  const float* fc_c_w = (const float*)d_in[12];
  const float* fc_c_b = (const float*)d_in[13];
  const float* fc_p_w = (const float*)d_in[14];
  const float* fc_p_b = (const float*)d_in[15];
  const float* ps     = (const float*)d_in[16];
  float* out = (float*)d_out;

  const int M = B_ * S_; // 4096
  float* w = (float*)d_ws;
  float*     qbuf   = w;                                   // M*3072 f32 (f16 alias after conv_q)
  _Float16*  kpe16  = (_Float16*)(qbuf + (size_t)M * 3072);           // B*T*64
  float*     Cpe    = (float*)(kpe16 + (size_t)B_ * T_ * ROPE_);      // T*512
  float*     C2     = Cpe + (size_t)T_ * C_;                          // T*128
  float*     P2     = C2  + (size_t)T_ * 128;                         // M*128
  _Float16*  pkv16  = (_Float16*)(P2 + (size_t)M * 128);              // B*T*512
  _Float16*  pkvT16 = pkv16  + (size_t)B_ * T_ * C_;                  // B*512*T
  _Float16*  W1T    = pkvT16 + (size_t)B_ * C_ * T_;                  // 16*512*128
  _Float16*  W2c    = W1T    + (size_t)16 * 512 * 128;                // 16*128*512
  float*     xreg   = (float*)(W2c + (size_t)16 * 128 * 512);         // M*2048 region
  float*     kvf    = xreg;                 // M*576 (dead before x2 write)
  float*     kvn    = xreg + (size_t)M * 576;  // M*512 (dead before x2 write)
  float*     x2     = xreg;                 // M*2048
  float*     qlp    = out;                  // d_out as scratch (dead after step 3)

  // 0. weight conversion (no deps)
  conv_wkvb<<<8192, 256, 0, stream>>>(wkvb, W1T, W2c);
  // 1. qlp = query @ wq_a^T
  gemm_f32<true,false><<<dim3(QR_/128, M/128), 256, 0, stream>>>(
      query, wq_a, nullptr, qlp, M, QR_, E_, E_, E_, QR_);
  // 2. LN in place
  ln_rows<<<M, 256, 0, stream>>>(qlp, qlp, q_ln_g, q_ln_b, QR_, QR_, QR_);
  // 3. qbuf = ql @ wq_b^T
  gemm_f32<true,false><<<dim3((H_*192)/128, M/128), 256, 0, stream>>>(
      qlp, wq_b, nullptr, qbuf, M, H_*192, QR_, QR_, QR_, H_*192);
  // 4. rope+normalize q_pe, f16 convert (in place)
  conv_q<<<M, 256, 0, stream>>>(qbuf, ps);
  // 5. kvf = key @ wkv_a^T
  gemm_f32<true,false><<<dim3(5, M/128), 256, 0, stream>>>(
      key, wkv_a, nullptr, kvf, M, 576, E_, E_, E_, 576);
  // 6. kvn = LN(kvf[:, :512])
  ln_rows<<<M, 256, 0, stream>>>(kvf, kvn, kv_ln_g, kv_ln_b, C_, 576, C_);
  // 7. kpe16
  rope_norm_k<<<dim3(T_, B_), 64, 0, stream>>>(kvf, kpe16);
  // 8. Cpe table
  pe_kernel<<<T_, 256, 0, stream>>>(Cpe);
  // 9. C2 = Cpe @ fc_c_w^T + b
  gemm_f32<true,true><<<dim3(1, T_/128), 256, 0, stream>>>(
      Cpe, fc_c_w, fc_c_b, C2, T_, 128, C_, C_, C_, 128);
  // 10. P2 = kvn @ fc_p_w^T + b
  gemm_f32<true,true><<<dim3(1, M/128), 256, 0, stream>>>(
      kvn, fc_p_w, fc_p_b, P2, M, 128, C_, C_, C_, 128);
  // 11. gate -> pkv16 + pkvT16
  gate_kernel<<<dim3(T_, B_), 64, 0, stream>>>(C2, P2, kvn, pkv16, pkvT16);
  // 12. MFMA flash attention -> x2 (overwrites kvf/kvn region)
  attn_mfma<<<dim3(S_/64, H_, B_), 256, 0, stream>>>(
      (const _Float16*)qbuf, W1T, W2c, pkv16, pkvT16, kpe16, x2);
  // 13. out = x2 @ wo^T
  gemm_f32<true,false><<<dim3(E_/128, M/128), 256, 0, stream>>>(
      x2, wo, nullptr, out, M, E_, H_*VH_, H_*VH_, H_*VH_, E_);
}

// Round 4
// 679.590 us; speedup vs baseline: 11.0233x; 5.1127x over previous
//
#include <hip/hip_runtime.h>
#include <math.h>

#define S_ 2048
#define B_ 2
#define H_ 16
#define E_ 2048
#define QR_ 1536
#define NOPE_ 128
#define ROPE_ 64
#define C_ 512
#define VH_ 128
#define T_ 1024
#define LN1E4 9.210340371976184f
#define SCALE_ 0.07216878364870323f  // 192^-0.5

typedef _Float16 half8 __attribute__((ext_vector_type(8)));
typedef float floatx4 __attribute__((ext_vector_type(4)));
#define MFMA16(a, b, c) __builtin_amdgcn_mfma_f32_16x16x32_f16(a, b, c, 0, 0, 0)

// ---------------- f32 -> f16 conversion (8 elems/thread) ----------------
__global__ __launch_bounds__(256) void conv16(
    const float* __restrict__ in, _Float16* __restrict__ out, int n8)
{
  int i = blockIdx.x * 256 + threadIdx.x;
  if (i >= n8) return;
  float4 a = ((const float4*)in)[2 * (size_t)i];
  float4 b = ((const float4*)in)[2 * (size_t)i + 1];
  half8 h = {(_Float16)a.x, (_Float16)a.y, (_Float16)a.z, (_Float16)a.w,
             (_Float16)b.x, (_Float16)b.y, (_Float16)b.z, (_Float16)b.w};
  *(half8*)(out + 8 * (size_t)i) = h;
}

// ---------------- f16 MFMA GEMM: C = A @ B^T, 128x128 tile, BK=64 ----------------
template<bool OUT16, bool NB>
__global__ __launch_bounds__(256) void gemm16(
    const _Float16* __restrict__ A, const _Float16* __restrict__ Bm,
    float* __restrict__ Cf, _Float16* __restrict__ Ch,
    int N, int K, int lda, int ldb, int ldc)
{
  __shared__ __align__(16) _Float16 Asl[128 * 72];
  __shared__ __align__(16) _Float16 Bsl[128 * 72];
  const int bm = blockIdx.y * 128, bn = blockIdx.x * 128;
  const int tid = threadIdx.x;
  const int w = tid >> 6, lane = tid & 63, l15 = lane & 15, g = lane >> 4;
  const int wm = (w >> 1) * 64, wn = (w & 1) * 64;
  floatx4 acc[4][4];
  #pragma unroll
  for (int i = 0; i < 4; ++i)
    #pragma unroll
    for (int j = 0; j < 4; ++j) acc[i][j] = (floatx4){0.f, 0.f, 0.f, 0.f};
  for (int k0 = 0; k0 < K; k0 += 64) {
    __syncthreads();
    #pragma unroll
    for (int p = 0; p < 4; ++p) {
      int c = tid + p * 256;
      int row = c >> 3, col = (c & 7) * 8;
      *(half8*)&Asl[row * 72 + col] =
          *(const half8*)(A + (size_t)(bm + row) * lda + k0 + col);
      half8 bv;
      #pragma unroll
      for (int j = 0; j < 8; ++j) bv[j] = (_Float16)0.f;
      int gb = bn + row;
      if (!NB || gb < N)
        bv = *(const half8*)(Bm + (size_t)gb * ldb + k0 + col);
      *(half8*)&Bsl[row * 72 + col] = bv;
    }
    __syncthreads();
    #pragma unroll
    for (int kk = 0; kk < 2; ++kk) {
      half8 af[4], bf[4];
      #pragma unroll
      for (int i = 0; i < 4; ++i) {
        af[i] = *(const half8*)&Asl[(wm + i * 16 + l15) * 72 + kk * 32 + g * 8];
        bf[i] = *(const half8*)&Bsl[(wn + i * 16 + l15) * 72 + kk * 32 + g * 8];
      }
      #pragma unroll
      for (int i = 0; i < 4; ++i)
        #pragma unroll
        for (int j = 0; j < 4; ++j)
          acc[i][j] = MFMA16(af[i], bf[j], acc[i][j]);
    }
  }
  #pragma unroll
  for (int i = 0; i < 4; ++i)
    #pragma unroll
    for (int j = 0; j < 4; ++j)
      #pragma unroll
      for (int r = 0; r < 4; ++r) {
        int row = bm + wm + i * 16 + g * 4 + r;
        int col = bn + wn + j * 16 + l15;
        if (!NB || col < N) {
          if (OUT16) Ch[(size_t)row * ldc + col] = (_Float16)acc[i][j][r];
          else       Cf[(size_t)row * ldc + col] = acc[i][j][r];
        }
      }
}

// ---------------- fp32 GEMM (small, bias): C = A @ B^T + bias ----------------
template<bool TRANS_B, bool BIAS>
__global__ __launch_bounds__(256) void gemm_f32(
    const float* __restrict__ A, const float* __restrict__ Bm,
    const float* __restrict__ bias, float* __restrict__ Cm,
    int M, int N, int K, int lda, int ldb, int ldc)
{
  __shared__ float As[8][132];
  __shared__ float Bs[8][132];
  const int bm = blockIdx.y * 128, bn = blockIdx.x * 128;
  const int tid = threadIdx.x;
  const int tx = tid & 15, ty = tid >> 4;
  float acc[8][8] = {};
  for (int k0 = 0; k0 < K; k0 += 8) {
    {
      int r = tid >> 1, kk = (tid & 1) * 4;
      int gr = bm + r;
      float4 v = make_float4(0.f, 0.f, 0.f, 0.f);
      if (gr < M) v = *(const float4*)(A + (size_t)gr * lda + k0 + kk);
      As[kk + 0][r] = v.x; As[kk + 1][r] = v.y; As[kk + 2][r] = v.z; As[kk + 3][r] = v.w;
    }
    {
      int r = tid >> 1, kk = (tid & 1) * 4;
      int gc = bn + r;
      float4 v = make_float4(0.f, 0.f, 0.f, 0.f);
      if (gc < N) v = *(const float4*)(Bm + (size_t)gc * ldb + k0 + kk);
      Bs[kk + 0][r] = v.x; Bs[kk + 1][r] = v.y; Bs[kk + 2][r] = v.z; Bs[kk + 3][r] = v.w;
    }
    __syncthreads();
    #pragma unroll
    for (int k = 0; k < 8; ++k) {
      float4 a0 = *(const float4*)&As[k][ty * 8];
      float4 a1 = *(const float4*)&As[k][ty * 8 + 4];
      float4 b0 = *(const float4*)&Bs[k][tx * 8];
      float4 b1 = *(const float4*)&Bs[k][tx * 8 + 4];
      float av[8] = {a0.x, a0.y, a0.z, a0.w, a1.x, a1.y, a1.z, a1.w};
      float bv[8] = {b0.x, b0.y, b0.z, b0.w, b1.x, b1.y, b1.z, b1.w};
      #pragma unroll
      for (int i = 0; i < 8; ++i)
        #pragma unroll
        for (int j = 0; j < 8; ++j)
          acc[i][j] = fmaf(av[i], bv[j], acc[i][j]);
    }
    __syncthreads();
  }
  #pragma unroll
  for (int i = 0; i < 8; ++i) {
    int row = bm + ty * 8 + i;
    if (row >= M) continue;
    #pragma unroll
    for (int j = 0; j < 8; ++j) {
      int col = bn + tx * 8 + j;
      if (col < N) {
        float v = acc[i][j];
        if (BIAS) v += bias[col];
        Cm[(size_t)row * ldc + col] = v;
      }
    }
  }
}

// ---------------- row LayerNorm (templated in/out) ----------------
template<typename TIN, bool OUT16>
__global__ __launch_bounds__(256) void ln_rows(
    const TIN* __restrict__ in, float* __restrict__ outf, _Float16* __restrict__ outh,
    const float* __restrict__ g, const float* __restrict__ bb,
    int L, int ldin, int ldout)
{
  const int row = blockIdx.x;
  const TIN* x = in + (size_t)row * ldin;
  float s = 0.f, s2 = 0.f;
  for (int i = threadIdx.x; i < L; i += 256) {
    float v = (float)x[i]; s += v; s2 += v * v;
  }
  #pragma unroll
  for (int off = 32; off; off >>= 1) {
    s  += __shfl_xor(s, off, 64);
    s2 += __shfl_xor(s2, off, 64);
  }
  __shared__ float rs[4], rs2[4];
  int lane = threadIdx.x & 63, w = threadIdx.x >> 6;
  if (lane == 0) { rs[w] = s; rs2[w] = s2; }
  __syncthreads();
  s  = rs[0] + rs[1] + rs[2] + rs[3];
  s2 = rs2[0] + rs2[1] + rs2[2] + rs2[3];
  float mean = s / L;
  float var = s2 / L - mean * mean;
  float inv = rsqrtf(var + 1e-5f);
  for (int i = threadIdx.x; i < L; i += 256) {
    float v = ((float)x[i] - mean) * inv * g[i] + bb[i];
    if (OUT16) outh[(size_t)row * ldout + i] = (_Float16)v;
    else       outf[(size_t)row * ldout + i] = v;
  }
}

// ------- rope + normalize q_pe in place (f16), fold ps*scale -------
__global__ __launch_bounds__(64) void rope_q16(_Float16* __restrict__ qb,
                                               const float* __restrict__ ps_ptr)
{
  const int idx = blockIdx.x;
  const int h = idx & (H_ - 1);
  const int row = idx >> 4;
  const int s = row & (S_ - 1);
  _Float16* p = qb + (size_t)row * 3072 + h * 192 + NOPE_;
  const int j = threadIdx.x;
  float o1 = 0.f, o2 = 0.f;
  if (j < 32) {
    float invf = expf(-(float)j * (LN1E4 / 32.f));
    float ang = (float)(S_ - 1 + s) * invf;
    float sn, cs; sincosf(ang, &sn, &cs);
    float x1 = (float)p[2 * j], x2 = (float)p[2 * j + 1];
    o1 = x1 * cs - x2 * sn;
    o2 = x1 * sn + x2 * cs;
  }
  float ss = o1 * o1 + o2 * o2;
  #pragma unroll
  for (int off = 32; off; off >>= 1) ss += __shfl_xor(ss, off, 64);
  float inv = ps_ptr[0] * SCALE_ / fmaxf(sqrtf(ss), 1e-12f);
  if (j < 32) {
    p[2 * j]     = (_Float16)(o1 * inv);
    p[2 * j + 1] = (_Float16)(o2 * inv);
  }
}

// ------- rope + normalize k_pe (odd rows) -> keff[b][h][t][128..192] all h -------
__global__ __launch_bounds__(64) void rope_k16(
    const _Float16* __restrict__ kvf16, _Float16* __restrict__ keff)
{
  const int t = blockIdx.x, b = blockIdx.y;
  const int srow = 2 * t + 1;
  const _Float16* p = kvf16 + ((size_t)(b * S_ + srow)) * 576 + C_;
  const int j = threadIdx.x;
  float o1 = 0.f, o2 = 0.f;
  if (j < 32) {
    float invf = expf(-(float)j * (LN1E4 / 32.f));
    float ang = (float)(S_ - 1 + srow) * invf;
    float sn, cs; sincosf(ang, &sn, &cs);
    float x1 = (float)p[2 * j], x2 = (float)p[2 * j + 1];
    o1 = x1 * cs - x2 * sn;
    o2 = x1 * sn + x2 * cs;
  }
  float ss = o1 * o1 + o2 * o2;
  #pragma unroll
  for (int off = 32; off; off >>= 1) ss += __shfl_xor(ss, off, 64);
  float nrm = fmaxf(sqrtf(ss), 1e-12f);
  if (j < 32) {
    _Float16 h1 = (_Float16)(o1 / nrm), h2 = (_Float16)(o2 / nrm);
    #pragma unroll
    for (int h = 0; h < H_; ++h) {
      _Float16* o = keff + ((size_t)((b * H_ + h) * T_) + t) * 192 + NOPE_;
      o[2 * j] = h1; o[2 * j + 1] = h2;
    }
  }
}

// ---------------- sinusoidal PE table ----------------
__global__ __launch_bounds__(256) void pe_kernel(float* __restrict__ Cpe)
{
  const int t = blockIdx.x;
  const int i = threadIdx.x;
  float dv = expf(-(float)(2 * i) * (LN1E4 / 512.f));
  float ang = (float)t * dv;
  float sn, cs; sincosf(ang, &sn, &cs);
  Cpe[(size_t)t * C_ + 2 * i] = sn;
  Cpe[(size_t)t * C_ + 2 * i + 1] = cs;
}

// ---------------- gate: pkv16[b][t] = w0*kvn[2t] + w1*kvn[2t+1] (f16) ----------------
__global__ __launch_bounds__(64) void gate_kernel(
    const float* __restrict__ C2, const float* __restrict__ P2,
    const float* __restrict__ kvn, _Float16* __restrict__ pkv16)
{
  const int t = blockIdx.x, b = blockIdx.y;
  const int j = threadIdx.x;
  const float* c2 = C2 + (size_t)t * 128;
  const float* p0 = P2 + ((size_t)(b * S_ + 2 * t)) * 128;
  const float* p1 = p0 + 128;
  float d0 = c2[j] * p0[j] + c2[j + 64] * p0[j + 64];
  float d1 = c2[j] * p1[j] + c2[j + 64] * p1[j + 64];
  #pragma unroll
  for (int off = 32; off; off >>= 1) {
    d0 += __shfl_xor(d0, off, 64);
    d1 += __shfl_xor(d1, off, 64);
  }
  float w0 = 1.f / (1.f + expf(-d0));
  float w1 = 1.f / (1.f + expf(-d1));
  const float* k0 = kvn + ((size_t)(b * S_ + 2 * t)) * C_;
  const float* k1 = k0 + C_;
  _Float16* o = pkv16 + ((size_t)(b * T_ + t)) * C_;
  #pragma unroll
  for (int it = 0; it < 2; ++it) {
    int c = j * 4 + it * 256;
    float4 a = *(const float4*)(k0 + c);
    float4 bb = *(const float4*)(k1 + c);
    o[c]     = (_Float16)(w0 * a.x + w1 * bb.x);
    o[c + 1] = (_Float16)(w0 * a.y + w1 * bb.y);
    o[c + 2] = (_Float16)(w0 * a.z + w1 * bb.z);
    o[c + 3] = (_Float16)(w0 * a.w + w1 * bb.w);
  }
}

// ---- conv_wkvb: W1c[h][d][c] = wkvb[h][d][c]*SCALE (f16); W2c[h][d][c] = wkvb[h][128+d][c] ----
__global__ __launch_bounds__(256) void conv_wkvb(
    const float* __restrict__ wkvb, _Float16* __restrict__ W1c,
    _Float16* __restrict__ W2c)
{
  int i = blockIdx.x * 256 + threadIdx.x;
  const int half = 16 * 128 * 512;
  if (i < half) {
    int c = i & 511, d = (i >> 9) & 127, h = i >> 16;
    W1c[i] = (_Float16)(wkvb[((size_t)(h * 256 + d)) * 512 + c] * SCALE_);
  } else {
    int j = i - half;
    int c = j & 511, d = (j >> 9) & 127, h = j >> 16;
    W2c[j] = (_Float16)wkvb[((size_t)(h * 256 + 128 + d)) * 512 + c];
  }
}

// ---- prep_kv: khead = pkv @ W1c^T -> keff[..][0:128]; vhead^T -> vT[b][h][d][t] ----
__global__ __launch_bounds__(256) void prep_kv(
    const _Float16* __restrict__ pkv16, const _Float16* __restrict__ W1c,
    const _Float16* __restrict__ W2c, _Float16* __restrict__ keff,
    _Float16* __restrict__ vT)
{
  const int b = blockIdx.z, h = blockIdx.y;
  const int tid = threadIdx.x, w = tid >> 6, lane = tid & 63;
  const int l15 = lane & 15, g = lane >> 4;
  const int t0 = blockIdx.x * 64 + w * 16;
  half8 ap[16];
  #pragma unroll
  for (int kk = 0; kk < 16; ++kk)
    ap[kk] = *(const half8*)(pkv16 + ((size_t)(b * T_) + t0 + l15) * 512 + kk * 32 + g * 8);
  floatx4 acc[8];
  #pragma unroll
  for (int i = 0; i < 8; ++i) acc[i] = (floatx4){0.f, 0.f, 0.f, 0.f};
  #pragma unroll
  for (int kk = 0; kk < 16; ++kk)
    #pragma unroll
    for (int cc = 0; cc < 8; ++cc)
      acc[cc] = MFMA16(ap[kk],
          *(const half8*)(W1c + ((size_t)(h * 128 + cc * 16 + l15)) * 512 + kk * 32 + g * 8),
          acc[cc]);
  #pragma unroll
  for (int cc = 0; cc < 8; ++cc)
    #pragma unroll
    for (int r = 0; r < 4; ++r)
      keff[((size_t)((b * H_ + h) * T_) + t0 + g * 4 + r) * 192 + cc * 16 + l15] =
          (_Float16)acc[cc][r];
  #pragma unroll
  for (int i = 0; i < 8; ++i) acc[i] = (floatx4){0.f, 0.f, 0.f, 0.f};
  #pragma unroll
  for (int kk = 0; kk < 16; ++kk)
    #pragma unroll
    for (int cc = 0; cc < 8; ++cc)
      acc[cc] = MFMA16(ap[kk],
          *(const half8*)(W2c + ((size_t)(h * 128 + cc * 16 + l15)) * 512 + kk * 32 + g * 8),
          acc[cc]);
  #pragma unroll
  for (int cc = 0; cc < 8; ++cc)
    #pragma unroll
    for (int r = 0; r < 4; ++r)
      vT[((size_t)((b * H_ + h) * 128) + cc * 16 + l15) * T_ + t0 + g * 4 + r] =
          (_Float16)acc[cc][r];
}

// ---------------- flash attention: d_qk=192, d_v=128, LDS-staged K/V ----------------
__global__ __launch_bounds__(256) void attn_flash(
    const _Float16* __restrict__ qb16, const _Float16* __restrict__ keff,
    const _Float16* __restrict__ vT, _Float16* __restrict__ x216)
{
  __shared__ __align__(16) _Float16 K_lds[64 * 200];  // 25.6 KB
  __shared__ __align__(16) _Float16 V_lds[128 * 72];  // 18.4 KB
  __shared__ __align__(16) _Float16 P_lds[64 * 72];   // 9.2 KB
  const int b = blockIdx.z, h = blockIdx.y, s0 = blockIdx.x * 64;
  const int tid = threadIdx.x, w = tid >> 6, lane = tid & 63;
  const int l15 = lane & 15, g = lane >> 4;
  const int rq = b * S_ + s0 + w * 16;
  const _Float16* qrow = qb16 + (size_t)(rq + l15) * 3072 + h * 192;
  half8 qA[6];
  #pragma unroll
  for (int kk = 0; kk < 6; ++kk) qA[kk] = *(const half8*)(qrow + kk * 32 + g * 8);
  floatx4 O[8];
  #pragma unroll
  for (int i = 0; i < 8; ++i) O[i] = (floatx4){0.f, 0.f, 0.f, 0.f};
  float m[4] = {-3e38f, -3e38f, -3e38f, -3e38f};
  float l[4] = {0.f, 0.f, 0.f, 0.f};
  const _Float16* kb = keff + (size_t)((b * H_ + h)) * T_ * 192;
  const _Float16* vb = vT   + (size_t)((b * H_ + h)) * 128 * T_;

  for (int kt = 0; kt < 16; ++kt) {
    const int t0 = kt * 64;
    __syncthreads();
    // stage K tile [64][192] (1536 16B-chunks, 6/thread)
    #pragma unroll
    for (int p = 0; p < 6; ++p) {
      int c = tid + p * 256;
      int row = c / 24, col = (c % 24) * 8;
      *(half8*)&K_lds[row * 200 + col] =
          *(const half8*)(kb + (size_t)(t0 + row) * 192 + col);
    }
    // stage V tile [128 d][64 t] (1024 chunks, 4/thread)
    #pragma unroll
    for (int p = 0; p < 4; ++p) {
      int c = tid + p * 256;
      int row = c >> 3, col = (c & 7) * 8;
      *(half8*)&V_lds[row * 72 + col] =
          *(const half8*)(vb + (size_t)row * T_ + t0 + col);
    }
    __syncthreads();
    // scores
    floatx4 sc[4];
    #pragma unroll
    for (int i = 0; i < 4; ++i) sc[i] = (floatx4){0.f, 0.f, 0.f, 0.f};
    #pragma unroll
    for (int kk = 0; kk < 6; ++kk)
      #pragma unroll
      for (int ct = 0; ct < 4; ++ct)
        sc[ct] = MFMA16(qA[kk],
            *(const half8*)&K_lds[(ct * 16 + l15) * 200 + kk * 32 + g * 8], sc[ct]);
    // online softmax
    float pm[4], sf[4], rs[4];
    #pragma unroll
    for (int r = 0; r < 4; ++r)
      pm[r] = fmaxf(fmaxf(sc[0][r], sc[1][r]), fmaxf(sc[2][r], sc[3][r]));
    #pragma unroll
    for (int off = 1; off < 16; off <<= 1)
      #pragma unroll
      for (int r = 0; r < 4; ++r) pm[r] = fmaxf(pm[r], __shfl_xor(pm[r], off, 64));
    #pragma unroll
    for (int r = 0; r < 4; ++r) {
      float mn = fmaxf(m[r], pm[r]);
      sf[r] = __expf(m[r] - mn);
      m[r] = mn; rs[r] = 0.f;
    }
    #pragma unroll
    for (int ct = 0; ct < 4; ++ct)
      #pragma unroll
      for (int r = 0; r < 4; ++r) {
        float e = __expf(sc[ct][r] - m[r]);
        sc[ct][r] = e; rs[r] += e;
      }
    #pragma unroll
    for (int off = 1; off < 16; off <<= 1)
      #pragma unroll
      for (int r = 0; r < 4; ++r) rs[r] += __shfl_xor(rs[r], off, 64);
    #pragma unroll
    for (int r = 0; r < 4; ++r) l[r] = l[r] * sf[r] + rs[r];
    #pragma unroll
    for (int cc = 0; cc < 8; ++cc) {
      O[cc][0] *= sf[0]; O[cc][1] *= sf[1]; O[cc][2] *= sf[2]; O[cc][3] *= sf[3];
    }
    // P -> LDS (wave-private rows; no barrier needed)
    #pragma unroll
    for (int ct = 0; ct < 4; ++ct)
      #pragma unroll
      for (int r = 0; r < 4; ++r)
        P_lds[(w * 16 + g * 4 + r) * 72 + ct * 16 + l15] = (_Float16)sc[ct][r];
    // PV
    #pragma unroll
    for (int kc = 0; kc < 2; ++kc) {
      half8 pa = *(const half8*)&P_lds[(w * 16 + l15) * 72 + kc * 32 + g * 8];
      #pragma unroll
      for (int cc = 0; cc < 8; ++cc)
        O[cc] = MFMA16(pa,
            *(const half8*)&V_lds[(cc * 16 + l15) * 72 + kc * 32 + g * 8], O[cc]);
    }
  }
  float il[4] = {1.f / l[0], 1.f / l[1], 1.f / l[2], 1.f / l[3]};
  #pragma unroll
  for (int cc = 0; cc < 8; ++cc)
    #pragma unroll
    for (int r = 0; r < 4; ++r)
      x216[(size_t)(rq + g * 4 + r) * 2048 + h * 128 + cc * 16 + l15] =
          (_Float16)(O[cc][r] * il[r]);
}

extern "C" void kernel_launch(void* const* d_in, const int* in_sizes, int n_in,
                              void* d_out, int out_size, void* d_ws, size_t ws_size,
                              hipStream_t stream)
{
  (void)in_sizes; (void)n_in; (void)out_size; (void)ws_size;
  const float* query  = (const float*)d_in[0];
  const float* key    = (const float*)d_in[1];
  const float* wq_a   = (const float*)d_in[3];
  const float* q_ln_g = (const float*)d_in[4];
  const float* q_ln_b = (const float*)d_in[5];
  const float* wq_b   = (const float*)d_in[6];
  const float* wkv_a  = (const float*)d_in[7];
  const float* kv_ln_g= (const float*)d_in[8];
  const float* kv_ln_b= (const float*)d_in[9];
  const float* wkvb   = (const float*)d_in[10];
  const float* wo     = (const float*)d_in[11];
  const float* fc_c_w = (const float*)d_in[12];
  const float* fc_c_b = (const float*)d_in[13];
  const float* fc_p_w = (const float*)d_in[14];
  const float* fc_p_b = (const float*)d_in[15];
  const float* ps     = (const float*)d_in[16];
  float* out = (float*)d_out;

  const int M = B_ * S_; // 4096
  // ---- workspace layout (halfs), ~111 MB total, heavy aliasing ----
  _Float16* hws   = (_Float16*)d_ws;
  _Float16* q16   = hws;                    // M*2048          (later: x216, same size)
  _Float16* key16 = q16   + (size_t)8388608;  // M*2048        (later: keff B*H*T*192 = 6,291,456 h)
  _Float16* wqa16 = key16 + (size_t)8388608;  // 1536*2048 = 3,145,728  (later: W1c|W2c 2,097,152)
  _Float16* wqb16 = wqa16 + (size_t)3145728;  // 3072*1536 = 4,718,592  (later: Cpe/C2/P2 fp32 4.5MB)
  _Float16* wkva16= wqb16 + (size_t)4718592;  // 576*2048 = 1,179,648   (later: pkv16 1,048,576)
  _Float16* wo16  = wkva16+ (size_t)1179648;  // 2048*2048 = 4,194,304
  _Float16* ql16  = wo16  + (size_t)4194304;  // M*1536 = 6,291,456     (later: vT 4,194,304)
  _Float16* qb16  = ql16  + (size_t)6291456;  // M*3072 = 12,582,912
  _Float16* kvf16 = qb16  + (size_t)12582912; // M*576 = 2,359,296
  float*    kvn   = (float*)(kvf16 + (size_t)2359296); // M*512 fp32
  // aliases
  _Float16* x216  = q16;
  _Float16* keff  = key16;
  _Float16* W1c   = wqa16;
  _Float16* W2c   = W1c + (size_t)1048576;
  float*    Cpe   = (float*)wqb16;
  float*    C2    = Cpe + (size_t)T_ * C_;
  float*    P2    = C2  + (size_t)T_ * 128;
  _Float16* pkv16 = wkva16;
  _Float16* vT    = ql16;
  float*    qlp   = out;  // d_out as fp32 scratch (dead after LN)

  // ---- conversions ----
  conv16<<<4096, 256, 0, stream>>>(query, q16,  1048576);
  conv16<<<4096, 256, 0, stream>>>(key,   key16, 1048576);
  conv16<<<1536, 256, 0, stream>>>(wq_a,  wqa16, 393216);
  conv16<<<2304, 256, 0, stream>>>(wq_b,  wqb16, 589824);
  conv16<<< 576, 256, 0, stream>>>(wkv_a, wkva16, 147456);
  conv16<<<2048, 256, 0, stream>>>(wo,    wo16,  524288);

  // 1. qlp = query @ wq_a^T  (f16 in, fp32 out in d_out)
  gemm16<false,false><<<dim3(QR_/128, M/128), 256, 0, stream>>>(
      q16, wqa16, qlp, nullptr, QR_, E_, E_, E_, QR_);
  // (wq_a16 dead -> W1c/W2c)
  conv_wkvb<<<8192, 256, 0, stream>>>(wkvb, W1c, W2c);
  // 2. LN -> ql16
  ln_rows<float,true><<<M, 256, 0, stream>>>(qlp, nullptr, ql16, q_ln_g, q_ln_b,
                                             QR_, QR_, QR_);
  // 3. qb16 = ql16 @ wq_b^T (f16 out)
  gemm16<true,false><<<dim3(3072/128, M/128), 256, 0, stream>>>(
      ql16, wqb16, nullptr, qb16, 3072, QR_, QR_, QR_, 3072);
  // 4. rope q_pe in place
  rope_q16<<<M * H_, 64, 0, stream>>>(qb16, ps);
  // 5. kvf16 = key @ wkv_a^T (f16 out, N=576 bounds)
  gemm16<true,true><<<dim3(5, M/128), 256, 0, stream>>>(
      key16, wkva16, nullptr, kvf16, 576, E_, E_, E_, 576);
  // 6. kvn = LN(kvf16[:, :512]) fp32
  ln_rows<_Float16,false><<<M, 256, 0, stream>>>(kvf16, kvn, nullptr, kv_ln_g, kv_ln_b,
                                                 C_, 576, C_);
  // 7. kpe -> keff[...,128:192] (key16 dead)
  rope_k16<<<dim3(T_, B_), 64, 0, stream>>>(kvf16, keff);
  // 8-10. PE table, C2, P2 (wq_b16 dead)
  pe_kernel<<<T_, 256, 0, stream>>>(Cpe);
  gemm_f32<true,true><<<dim3(1, T_/128), 256, 0, stream>>>(
      Cpe, fc_c_w, fc_c_b, C2, T_, 128, C_, C_, C_, 128);
  gemm_f32<true,true><<<dim3(1, M/128), 256, 0, stream>>>(
      kvn, fc_p_w, fc_p_b, P2, M, 128, C_, C_, C_, 128);
  // 11. gate -> pkv16 (wkv_a16 dead)
  gate_kernel<<<dim3(T_, B_), 64, 0, stream>>>(C2, P2, kvn, pkv16);
  // 12. khead/vhead -> keff[...,0:128], vT (ql16 dead)
  prep_kv<<<dim3(T_/64, H_, B_), 256, 0, stream>>>(pkv16, W1c, W2c, keff, vT);
  // 13. flash attention -> x216 (q16 dead)
  attn_flash<<<dim3(S_/64, H_, B_), 256, 0, stream>>>(qb16, keff, vT, x216);
  // 14. out = x216 @ wo16^T (fp32 out, overwrites qlp scratch)
  gemm16<false,false><<<dim3(E_/128, M/128), 256, 0, stream>>>(
      x216, wo16, out, nullptr, E_, E_, E_, E_, E_);
}

// Round 5
// 495.153 us; speedup vs baseline: 15.1294x; 1.3725x over previous
//
#include <hip/hip_runtime.h>
#include <math.h>

#define S_ 2048
#define B_ 2
#define H_ 16
#define E_ 2048
#define QR_ 1536
#define NOPE_ 128
#define ROPE_ 64
#define C_ 512
#define VH_ 128
#define T_ 1024
#define LN1E4 9.210340371976184f
#define SCALE_ 0.07216878364870323f  // 192^-0.5

typedef _Float16 half8 __attribute__((ext_vector_type(8)));
typedef float floatx4 __attribute__((ext_vector_type(4)));
#define MFMA16(a, b, c) __builtin_amdgcn_mfma_f32_16x16x32_f16(a, b, c, 0, 0, 0)

__device__ __forceinline__ void gload16(const _Float16* g, _Float16* l) {
  __builtin_amdgcn_global_load_lds(
      (__attribute__((address_space(1))) const void*)g,
      (__attribute__((address_space(3))) void*)l, 16, 0, 0);
}

// ---------------- fused f32 -> f16 conversion for 8 tensors ----------------
__global__ __launch_bounds__(256) void conv_all(
    const float* __restrict__ q, const float* __restrict__ k,
    const float* __restrict__ wqa, const float* __restrict__ wqb,
    const float* __restrict__ wkva, const float* __restrict__ wo,
    const float* __restrict__ fcc, const float* __restrict__ fcp,
    _Float16* q16, _Float16* k16, _Float16* wqa16, _Float16* wqb16,
    _Float16* wkva16, _Float16* wo16, _Float16* fcc16, _Float16* fcp16)
{
  size_t i = (size_t)blockIdx.x * 256 + threadIdx.x;  // half8-chunk index
  const float* in; _Float16* out; size_t off;
  if      (i < 1048576) { in = q;    out = q16;    off = i; }
  else if (i < 2097152) { in = k;    out = k16;    off = i - 1048576; }
  else if (i < 2490368) { in = wqa;  out = wqa16;  off = i - 2097152; }
  else if (i < 3080192) { in = wqb;  out = wqb16;  off = i - 2490368; }
  else if (i < 3227648) { in = wkva; out = wkva16; off = i - 3080192; }
  else if (i < 3751936) { in = wo;   out = wo16;   off = i - 3227648; }
  else if (i < 3760128) { in = fcc;  out = fcc16;  off = i - 3751936; }
  else                  { in = fcp;  out = fcp16;  off = i - 3760128; }
  float4 a = ((const float4*)in)[2 * off];
  float4 b = ((const float4*)in)[2 * off + 1];
  half8 h = {(_Float16)a.x, (_Float16)a.y, (_Float16)a.z, (_Float16)a.w,
             (_Float16)b.x, (_Float16)b.y, (_Float16)b.z, (_Float16)b.w};
  *(half8*)(out + 8 * off) = h;
}

// ------- f16 MFMA GEMM, m97-structure: global_load_lds + XOR-swizzled LDS -------
// C = A @ B^T (+bias). 128x128 tile, BK=64, 4 waves, single-buffered 32KB LDS.
template<bool OUT16, bool NB, bool BIAS>
__global__ __launch_bounds__(256) void gemm16(
    const _Float16* __restrict__ A, const _Float16* __restrict__ Bm,
    const float* __restrict__ bias, float* __restrict__ Cf,
    _Float16* __restrict__ Ch, int N, int K, int lda, int ldb, int ldc)
{
  __shared__ __align__(16) _Float16 Asl[128 * 64];
  __shared__ __align__(16) _Float16 Bsl[128 * 64];
  const int bm = blockIdx.y * 128, bn = blockIdx.x * 128;
  const int tid = threadIdx.x;
  const int w = tid >> 6, lane = tid & 63, l15 = lane & 15, g = lane >> 4;
  const int wm = (w >> 1) * 64, wn = (w & 1) * 64;
  // staging: lane covers LDS slot (row, lane&7); that slot stores global
  // chunk (lane&7)^(row&7). row = w*32 + i*8 + (lane>>3)  -> row&7 = lane>>3.
  const int srow = w * 32 + (lane >> 3);
  const int sch  = (lane & 7) ^ (lane >> 3);   // global chunk this lane fetches
  floatx4 acc[4][4];
  #pragma unroll
  for (int i = 0; i < 4; ++i)
    #pragma unroll
    for (int j = 0; j < 4; ++j) acc[i][j] = (floatx4){0.f, 0.f, 0.f, 0.f};
  for (int k0 = 0; k0 < K; k0 += 64) {
    __syncthreads();
    #pragma unroll
    for (int i = 0; i < 4; ++i)
      gload16(A + (size_t)(bm + srow + i * 8) * lda + k0 + sch * 8,
              Asl + (w * 256 + i * 64) * 8);
    #pragma unroll
    for (int i = 0; i < 4; ++i)
      gload16(Bm + (size_t)(bn + srow + i * 8) * ldb + k0 + sch * 8,
              Bsl + (w * 256 + i * 64) * 8);
    __syncthreads();
    #pragma unroll
    for (int kk = 0; kk < 2; ++kk) {
      half8 af[4], bf[4];
      const int sw = ((kk * 4 + g) ^ (l15 & 7)) * 8;  // swizzled read chunk
      #pragma unroll
      for (int i = 0; i < 4; ++i) {
        af[i] = *(const half8*)&Asl[(wm + i * 16 + l15) * 64 + sw];
        bf[i] = *(const half8*)&Bsl[(wn + i * 16 + l15) * 64 + sw];
      }
      #pragma unroll
      for (int i = 0; i < 4; ++i)
        #pragma unroll
        for (int j = 0; j < 4; ++j)
          acc[i][j] = MFMA16(af[i], bf[j], acc[i][j]);
    }
  }
  #pragma unroll
  for (int i = 0; i < 4; ++i)
    #pragma unroll
    for (int j = 0; j < 4; ++j)
      #pragma unroll
      for (int r = 0; r < 4; ++r) {
        int row = bm + wm + i * 16 + g * 4 + r;
        int col = bn + wn + j * 16 + l15;
        if (!NB || col < N) {
          float v = acc[i][j][r];
          if (BIAS) v += bias[col];
          if (OUT16) Ch[(size_t)row * ldc + col] = (_Float16)v;
          else       Cf[(size_t)row * ldc + col] = v;
        }
      }
}

// ---------------- row LayerNorm (templated in/out) ----------------
template<typename TIN, bool OUT16>
__global__ __launch_bounds__(256) void ln_rows(
    const TIN* __restrict__ in, float* __restrict__ outf, _Float16* __restrict__ outh,
    const float* __restrict__ g, const float* __restrict__ bb,
    int L, int ldin, int ldout)
{
  const int row = blockIdx.x;
  const TIN* x = in + (size_t)row * ldin;
  float s = 0.f, s2 = 0.f;
  for (int i = threadIdx.x; i < L; i += 256) {
    float v = (float)x[i]; s += v; s2 += v * v;
  }
  #pragma unroll
  for (int off = 32; off; off >>= 1) {
    s  += __shfl_xor(s, off, 64);
    s2 += __shfl_xor(s2, off, 64);
  }
  __shared__ float rs[4], rs2[4];
  int lane = threadIdx.x & 63, w = threadIdx.x >> 6;
  if (lane == 0) { rs[w] = s; rs2[w] = s2; }
  __syncthreads();
  s  = rs[0] + rs[1] + rs[2] + rs[3];
  s2 = rs2[0] + rs2[1] + rs2[2] + rs2[3];
  float mean = s / L;
  float var = s2 / L - mean * mean;
  float inv = rsqrtf(var + 1e-5f);
  for (int i = threadIdx.x; i < L; i += 256) {
    float v = ((float)x[i] - mean) * inv * g[i] + bb[i];
    if (OUT16) outh[(size_t)row * ldout + i] = (_Float16)v;
    else       outf[(size_t)row * ldout + i] = v;
  }
}

// ------- rope + normalize q_pe in place (f16), fold ps*scale -------
__global__ __launch_bounds__(64) void rope_q16(_Float16* __restrict__ qb,
                                               const float* __restrict__ ps_ptr)
{
  const int idx = blockIdx.x;
  const int h = idx & (H_ - 1);
  const int row = idx >> 4;
  const int s = row & (S_ - 1);
  _Float16* p = qb + (size_t)row * 3072 + h * 192 + NOPE_;
  const int j = threadIdx.x;
  float o1 = 0.f, o2 = 0.f;
  if (j < 32) {
    float invf = expf(-(float)j * (LN1E4 / 32.f));
    float ang = (float)(S_ - 1 + s) * invf;
    float sn, cs; sincosf(ang, &sn, &cs);
    float x1 = (float)p[2 * j], x2 = (float)p[2 * j + 1];
    o1 = x1 * cs - x2 * sn;
    o2 = x1 * sn + x2 * cs;
  }
  float ss = o1 * o1 + o2 * o2;
  #pragma unroll
  for (int off = 32; off; off >>= 1) ss += __shfl_xor(ss, off, 64);
  float inv = ps_ptr[0] * SCALE_ / fmaxf(sqrtf(ss), 1e-12f);
  if (j < 32) {
    p[2 * j]     = (_Float16)(o1 * inv);
    p[2 * j + 1] = (_Float16)(o2 * inv);
  }
}

// ------- rope + normalize k_pe (odd rows) -> keff[b][h][t][128..192] all h -------
__global__ __launch_bounds__(64) void rope_k16(
    const _Float16* __restrict__ kvf16, _Float16* __restrict__ keff)
{
  const int t = blockIdx.x, b = blockIdx.y;
  const int srow = 2 * t + 1;
  const _Float16* p = kvf16 + ((size_t)(b * S_ + srow)) * 576 + C_;
  const int j = threadIdx.x;
  float o1 = 0.f, o2 = 0.f;
  if (j < 32) {
    float invf = expf(-(float)j * (LN1E4 / 32.f));
    float ang = (float)(S_ - 1 + srow) * invf;
    float sn, cs; sincosf(ang, &sn, &cs);
    float x1 = (float)p[2 * j], x2 = (float)p[2 * j + 1];
    o1 = x1 * cs - x2 * sn;
    o2 = x1 * sn + x2 * cs;
  }
  float ss = o1 * o1 + o2 * o2;
  #pragma unroll
  for (int off = 32; off; off >>= 1) ss += __shfl_xor(ss, off, 64);
  float nrm = fmaxf(sqrtf(ss), 1e-12f);
  if (j < 32) {
    _Float16 h1 = (_Float16)(o1 / nrm), h2 = (_Float16)(o2 / nrm);
    #pragma unroll
    for (int h = 0; h < H_; ++h) {
      _Float16* o = keff + ((size_t)((b * H_ + h) * T_) + t) * 192 + NOPE_;
      o[2 * j] = h1; o[2 * j + 1] = h2;
    }
  }
}

// ---------------- sinusoidal PE table (f16) ----------------
__global__ __launch_bounds__(256) void pe16(_Float16* __restrict__ Cpe16)
{
  const int t = blockIdx.x;
  const int i = threadIdx.x;
  float dv = expf(-(float)(2 * i) * (LN1E4 / 512.f));
  float ang = (float)t * dv;
  float sn, cs; sincosf(ang, &sn, &cs);
  Cpe16[(size_t)t * C_ + 2 * i]     = (_Float16)sn;
  Cpe16[(size_t)t * C_ + 2 * i + 1] = (_Float16)cs;
}

// ---------------- gate: pkv16[b][t] = w0*kvn[2t] + w1*kvn[2t+1] (all f16 in) ----------------
__global__ __launch_bounds__(64) void gate_kernel(
    const _Float16* __restrict__ C2, const _Float16* __restrict__ P2,
    const _Float16* __restrict__ kvn16, _Float16* __restrict__ pkv16)
{
  const int t = blockIdx.x, b = blockIdx.y;
  const int j = threadIdx.x;
  const _Float16* c2 = C2 + (size_t)t * 128;
  const _Float16* p0 = P2 + ((size_t)(b * S_ + 2 * t)) * 128;
  const _Float16* p1 = p0 + 128;
  float d0 = (float)c2[j] * (float)p0[j] + (float)c2[j + 64] * (float)p0[j + 64];
  float d1 = (float)c2[j] * (float)p1[j] + (float)c2[j + 64] * (float)p1[j + 64];
  #pragma unroll
  for (int off = 32; off; off >>= 1) {
    d0 += __shfl_xor(d0, off, 64);
    d1 += __shfl_xor(d1, off, 64);
  }
  float w0 = 1.f / (1.f + expf(-d0));
  float w1 = 1.f / (1.f + expf(-d1));
  const _Float16* k0 = kvn16 + ((size_t)(b * S_ + 2 * t)) * C_;
  const _Float16* k1 = k0 + C_;
  _Float16* o = pkv16 + ((size_t)(b * T_ + t)) * C_;
  #pragma unroll
  for (int it = 0; it < 2; ++it) {
    int c = j * 4 + it * 256;
    #pragma unroll
    for (int u = 0; u < 4; ++u)
      o[c + u] = (_Float16)(w0 * (float)k0[c + u] + w1 * (float)k1[c + u]);
  }
}

// ---- conv_wkvb: W1c[h][d][c] = wkvb[h][d][c]*SCALE (f16); W2c = wkvb[h][128+d][c] ----
__global__ __launch_bounds__(256) void conv_wkvb(
    const float* __restrict__ wkvb, _Float16* __restrict__ W1c,
    _Float16* __restrict__ W2c)
{
  int i = blockIdx.x * 256 + threadIdx.x;
  const int half = 16 * 128 * 512;
  if (i < half) {
    int c = i & 511, d = (i >> 9) & 127, h = i >> 16;
    W1c[i] = (_Float16)(wkvb[((size_t)(h * 256 + d)) * 512 + c] * SCALE_);
  } else {
    int j = i - half;
    int c = j & 511, d = (j >> 9) & 127, h = j >> 16;
    W2c[j] = (_Float16)wkvb[((size_t)(h * 256 + 128 + d)) * 512 + c];
  }
}

// ---- prep_kv: khead = pkv @ W1c^T -> keff[..][0:128]; vhead^T -> vT[b][h][d][t] ----
__global__ __launch_bounds__(256) void prep_kv(
    const _Float16* __restrict__ pkv16, const _Float16* __restrict__ W1c,
    const _Float16* __restrict__ W2c, _Float16* __restrict__ keff,
    _Float16* __restrict__ vT)
{
  const int b = blockIdx.z, h = blockIdx.y;
  const int tid = threadIdx.x, w = tid >> 6, lane = tid & 63;
  const int l15 = lane & 15, g = lane >> 4;
  const int t0 = blockIdx.x * 64 + w * 16;
  half8 ap[16];
  #pragma unroll
  for (int kk = 0; kk < 16; ++kk)
    ap[kk] = *(const half8*)(pkv16 + ((size_t)(b * T_) + t0 + l15) * 512 + kk * 32 + g * 8);
  floatx4 acc[8];
  #pragma unroll
  for (int i = 0; i < 8; ++i) acc[i] = (floatx4){0.f, 0.f, 0.f, 0.f};
  #pragma unroll
  for (int kk = 0; kk < 16; ++kk)
    #pragma unroll
    for (int cc = 0; cc < 8; ++cc)
      acc[cc] = MFMA16(ap[kk],
          *(const half8*)(W1c + ((size_t)(h * 128 + cc * 16 + l15)) * 512 + kk * 32 + g * 8),
          acc[cc]);
  #pragma unroll
  for (int cc = 0; cc < 8; ++cc)
    #pragma unroll
    for (int r = 0; r < 4; ++r)
      keff[((size_t)((b * H_ + h) * T_) + t0 + g * 4 + r) * 192 + cc * 16 + l15] =
          (_Float16)acc[cc][r];
  #pragma unroll
  for (int i = 0; i < 8; ++i) acc[i] = (floatx4){0.f, 0.f, 0.f, 0.f};
  #pragma unroll
  for (int kk = 0; kk < 16; ++kk)
    #pragma unroll
    for (int cc = 0; cc < 8; ++cc)
      acc[cc] = MFMA16(ap[kk],
          *(const half8*)(W2c + ((size_t)(h * 128 + cc * 16 + l15)) * 512 + kk * 32 + g * 8),
          acc[cc]);
  #pragma unroll
  for (int cc = 0; cc < 8; ++cc)
    #pragma unroll
    for (int r = 0; r < 4; ++r)
      vT[((size_t)((b * H_ + h) * 128) + cc * 16 + l15) * T_ + t0 + g * 4 + r] =
          (_Float16)acc[cc][r];
}

// ------- flash attention: d_qk=192, d_v=128; 2 q-tiles/block sharing K/V staging -------
__global__ __launch_bounds__(256, 2) void attn_flash(
    const _Float16* __restrict__ qb16, const _Float16* __restrict__ keff,
    const _Float16* __restrict__ vT, _Float16* __restrict__ x216)
{
  __shared__ __align__(16) _Float16 K_lds[64 * 200];  // 25.6 KB
  __shared__ __align__(16) _Float16 V_lds[128 * 72];  // 18.4 KB
  __shared__ __align__(16) _Float16 P_lds[64 * 72];   // 9.2 KB
  const int b = blockIdx.z, h = blockIdx.y;
  const int tid = threadIdx.x, w = tid >> 6, lane = tid & 63;
  const int l15 = lane & 15, g = lane >> 4;
  const int rq0 = b * S_ + blockIdx.x * 64 + w * 16;   // tile u=0
  const int rq1 = rq0 + 1024;                          // tile u=1
  half8 qA[2][6];
  #pragma unroll
  for (int u = 0; u < 2; ++u) {
    const _Float16* qrow =
        qb16 + (size_t)((u ? rq1 : rq0) + l15) * 3072 + h * 192;
    #pragma unroll
    for (int kk = 0; kk < 6; ++kk) qA[u][kk] = *(const half8*)(qrow + kk * 32 + g * 8);
  }
  floatx4 O[2][8];
  float m[2][4], l[2][4];
  #pragma unroll
  for (int u = 0; u < 2; ++u) {
    #pragma unroll
    for (int i = 0; i < 8; ++i) O[u][i] = (floatx4){0.f, 0.f, 0.f, 0.f};
    #pragma unroll
    for (int r = 0; r < 4; ++r) { m[u][r] = -3e38f; l[u][r] = 0.f; }
  }
  const _Float16* kb = keff + (size_t)(b * H_ + h) * T_ * 192;
  const _Float16* vb = vT   + (size_t)(b * H_ + h) * 128 * T_;

  for (int kt = 0; kt < 16; ++kt) {
    const int t0 = kt * 64;
    __syncthreads();
    #pragma unroll
    for (int p = 0; p < 6; ++p) {     // K tile [64][192]
      int c = tid + p * 256;
      int row = c / 24, col = (c % 24) * 8;
      *(half8*)&K_lds[row * 200 + col] =
          *(const half8*)(kb + (size_t)(t0 + row) * 192 + col);
    }
    #pragma unroll
    for (int p = 0; p < 4; ++p) {     // V tile [128 d][64 t]
      int c = tid + p * 256;
      int row = c >> 3, col = (c & 7) * 8;
      *(half8*)&V_lds[row * 72 + col] =
          *(const half8*)(vb + (size_t)row * T_ + t0 + col);
    }
    __syncthreads();
    #pragma unroll
    for (int u = 0; u < 2; ++u) {
      floatx4 sc[4];
      #pragma unroll
      for (int i = 0; i < 4; ++i) sc[i] = (floatx4){0.f, 0.f, 0.f, 0.f};
      #pragma unroll
      for (int kk = 0; kk < 6; ++kk)
        #pragma unroll
        for (int ct = 0; ct < 4; ++ct)
          sc[ct] = MFMA16(qA[u][kk],
              *(const half8*)&K_lds[(ct * 16 + l15) * 200 + kk * 32 + g * 8], sc[ct]);
      float pm[4], sf[4], rs[4];
      #pragma unroll
      for (int r = 0; r < 4; ++r)
        pm[r] = fmaxf(fmaxf(sc[0][r], sc[1][r]), fmaxf(sc[2][r], sc[3][r]));
      #pragma unroll
      for (int off = 1; off < 16; off <<= 1)
        #pragma unroll
        for (int r = 0; r < 4; ++r) pm[r] = fmaxf(pm[r], __shfl_xor(pm[r], off, 64));
      #pragma unroll
      for (int r = 0; r < 4; ++r) {
        float mn = fmaxf(m[u][r], pm[r]);
        sf[r] = __expf(m[u][r] - mn);
        m[u][r] = mn; rs[r] = 0.f;
      }
      #pragma unroll
      for (int ct = 0; ct < 4; ++ct)
        #pragma unroll
        for (int r = 0; r < 4; ++r) {
          float e = __expf(sc[ct][r] - m[u][r]);
          sc[ct][r] = e; rs[r] += e;
        }
      #pragma unroll
      for (int off = 1; off < 16; off <<= 1)
        #pragma unroll
        for (int r = 0; r < 4; ++r) rs[r] += __shfl_xor(rs[r], off, 64);
      #pragma unroll
      for (int r = 0; r < 4; ++r) l[u][r] = l[u][r] * sf[r] + rs[r];
      #pragma unroll
      for (int cc = 0; cc < 8; ++cc) {
        O[u][cc][0] *= sf[0]; O[u][cc][1] *= sf[1];
        O[u][cc][2] *= sf[2]; O[u][cc][3] *= sf[3];
      }
      #pragma unroll
      for (int ct = 0; ct < 4; ++ct)
        #pragma unroll
        for (int r = 0; r < 4; ++r)
          P_lds[(w * 16 + g * 4 + r) * 72 + ct * 16 + l15] = (_Float16)sc[ct][r];
      #pragma unroll
      for (int kc = 0; kc < 2; ++kc) {
        half8 pa = *(const half8*)&P_lds[(w * 16 + l15) * 72 + kc * 32 + g * 8];
        #pragma unroll
        for (int cc = 0; cc < 8; ++cc)
          O[u][cc] = MFMA16(pa,
              *(const half8*)&V_lds[(cc * 16 + l15) * 72 + kc * 32 + g * 8], O[u][cc]);
      }
    }
  }
  #pragma unroll
  for (int u = 0; u < 2; ++u) {
    const int rq = u ? rq1 : rq0;
    float il[4] = {1.f / l[u][0], 1.f / l[u][1], 1.f / l[u][2], 1.f / l[u][3]};
    #pragma unroll
    for (int cc = 0; cc < 8; ++cc)
      #pragma unroll
      for (int r = 0; r < 4; ++r)
        x216[(size_t)(rq + g * 4 + r) * 2048 + h * 128 + cc * 16 + l15] =
            (_Float16)(O[u][cc][r] * il[r]);
  }
}

extern "C" void kernel_launch(void* const* d_in, const int* in_sizes, int n_in,
                              void* d_out, int out_size, void* d_ws, size_t ws_size,
                              hipStream_t stream)
{
  (void)in_sizes; (void)n_in; (void)out_size; (void)ws_size;
  const float* query  = (const float*)d_in[0];
  const float* key    = (const float*)d_in[1];
  const float* wq_a   = (const float*)d_in[3];
  const float* q_ln_g = (const float*)d_in[4];
  const float* q_ln_b = (const float*)d_in[5];
  const float* wq_b   = (const float*)d_in[6];
  const float* wkv_a  = (const float*)d_in[7];
  const float* kv_ln_g= (const float*)d_in[8];
  const float* kv_ln_b= (const float*)d_in[9];
  const float* wkvb   = (const float*)d_in[10];
  const float* wo     = (const float*)d_in[11];
  const float* fc_c_w = (const float*)d_in[12];
  const float* fc_c_b = (const float*)d_in[13];
  const float* fc_p_w = (const float*)d_in[14];
  const float* fc_p_b = (const float*)d_in[15];
  const float* ps     = (const float*)d_in[16];
  float* out = (float*)d_out;

  const int M = B_ * S_; // 4096
  // ---- workspace layout (halves), ~108 MB, heavy aliasing ----
  _Float16* hws   = (_Float16*)d_ws;
  _Float16* q16   = hws;                      // 8,388,608   (later: x216)
  _Float16* key16 = q16   + (size_t)8388608;  // 8,388,608   (later: keff 6,291,456)
  _Float16* wqa16 = key16 + (size_t)8388608;  // 3,145,728   (later: W1c|W2c 2,097,152)
  _Float16* wqb16 = wqa16 + (size_t)3145728;  // 4,718,592   (later: Cpe16/C2h/P2h)
  _Float16* wkva16= wqb16 + (size_t)4718592;  // 1,179,648   (later: pkv16 1,048,576)
  _Float16* wo16  = wkva16+ (size_t)1179648;  // 4,194,304
  _Float16* ql16  = wo16  + (size_t)4194304;  // 6,291,456   (later: vT 4,194,304)
  _Float16* qb16  = ql16  + (size_t)6291456;  // 12,582,912
  _Float16* kvf16 = qb16  + (size_t)12582912; // 2,359,296
  _Float16* kvn16 = kvf16 + (size_t)2359296;  // 2,097,152
  _Float16* fcc16 = kvn16 + (size_t)2097152;  // 65,536
  _Float16* fcp16 = fcc16 + (size_t)65536;    // 65,536
  // aliases
  _Float16* x216  = q16;
  _Float16* keff  = key16;
  _Float16* W1c   = wqa16;
  _Float16* W2c   = W1c + (size_t)1048576;
  _Float16* Cpe16 = wqb16;
  _Float16* C2h   = Cpe16 + (size_t)T_ * C_;
  _Float16* P2h   = C2h + (size_t)T_ * 128;
  _Float16* pkv16 = wkva16;
  _Float16* vT    = ql16;
  float*    qlp   = out;  // d_out as fp32 scratch (dead after LN)

  // 0. all f32->f16 conversions in one kernel
  conv_all<<<14720, 256, 0, stream>>>(query, key, wq_a, wq_b, wkv_a, wo, fc_c_w, fc_p_w,
                                      q16, key16, wqa16, wqb16, wkva16, wo16, fcc16, fcp16);
  // 1. qlp = query @ wq_a^T (fp32 out in d_out)
  gemm16<false,false,false><<<dim3(QR_/128, M/128), 256, 0, stream>>>(
      q16, wqa16, nullptr, qlp, nullptr, QR_, E_, E_, E_, QR_);
  // (wqa16 dead -> W1c/W2c)
  conv_wkvb<<<8192, 256, 0, stream>>>(wkvb, W1c, W2c);
  // 2. LN -> ql16
  ln_rows<float,true><<<M, 256, 0, stream>>>(qlp, nullptr, ql16, q_ln_g, q_ln_b,
                                             QR_, QR_, QR_);
  // 3. qb16 = ql16 @ wq_b^T
  gemm16<true,false,false><<<dim3(3072/128, M/128), 256, 0, stream>>>(
      ql16, wqb16, nullptr, nullptr, qb16, 3072, QR_, QR_, QR_, 3072);
  // 4. rope q_pe in place
  rope_q16<<<M * H_, 64, 0, stream>>>(qb16, ps);
  // 5. kvf16 = key @ wkv_a^T (N=576, bounds-checked writes; B overreads stay in d_ws)
  gemm16<true,true,false><<<dim3(5, M/128), 256, 0, stream>>>(
      key16, wkva16, nullptr, nullptr, kvf16, 576, E_, E_, E_, 576);
  // 6. kvn16 = LN(kvf16[:, :512])
  ln_rows<_Float16,true><<<M, 256, 0, stream>>>(kvf16, nullptr, kvn16, kv_ln_g, kv_ln_b,
                                                C_, 576, C_);
  // 7. kpe -> keff[...,128:192] (key16 dead)
  rope_k16<<<dim3(T_, B_), 64, 0, stream>>>(kvf16, keff);
  // 8. PE table f16 (wqb16 dead)
  pe16<<<T_, 256, 0, stream>>>(Cpe16);
  // 9. C2h = Cpe16 @ fcc16^T + fc_c_b
  gemm16<true,false,true><<<dim3(1, T_/128), 256, 0, stream>>>(
      Cpe16, fcc16, fc_c_b, nullptr, C2h, 128, C_, C_, C_, 128);
  // 10. P2h = kvn16 @ fcp16^T + fc_p_b
  gemm16<true,false,true><<<dim3(1, M/128), 256, 0, stream>>>(
      kvn16, fcp16, fc_p_b, nullptr, P2h, 128, C_, C_, C_, 128);
  // 11. gate -> pkv16 (wkva16 dead)
  gate_kernel<<<dim3(T_, B_), 64, 0, stream>>>(C2h, P2h, kvn16, pkv16);
  // 12. khead/vhead -> keff[...,0:128], vT (ql16 dead)
  prep_kv<<<dim3(T_/64, H_, B_), 256, 0, stream>>>(pkv16, W1c, W2c, keff, vT);
  // 13. flash attention, 2 q-tiles/block -> x216 (q16 dead)
  attn_flash<<<dim3(16, H_, B_), 256, 0, stream>>>(qb16, keff, vT, x216);
  // 14. out = x216 @ wo16^T (fp32 out)
  gemm16<false,false,false><<<dim3(E_/128, M/128), 256, 0, stream>>>(
      x216, wo16, nullptr, out, nullptr, E_, E_, E_, E_, E_);
}

// Round 6
// 462.709 us; speedup vs baseline: 16.1902x; 1.0701x over previous
//
#include <hip/hip_runtime.h>
#include <math.h>

#define S_ 2048
#define B_ 2
#define H_ 16
#define E_ 2048
#define QR_ 1536
#define NOPE_ 128
#define ROPE_ 64
#define C_ 512
#define VH_ 128
#define T_ 1024
#define LN1E4 9.210340371976184f
#define SCALE_ 0.07216878364870323f  // 192^-0.5

typedef _Float16 half8 __attribute__((ext_vector_type(8)));
typedef float floatx4 __attribute__((ext_vector_type(4)));
#define MFMA16(a, b, c) __builtin_amdgcn_mfma_f32_16x16x32_f16(a, b, c, 0, 0, 0)

__device__ __forceinline__ void gload16(const _Float16* g, _Float16* l) {
  __builtin_amdgcn_global_load_lds(
      (__attribute__((address_space(1))) const void*)g,
      (__attribute__((address_space(3))) void*)l, 16, 0, 0);
}

// bijective XCD-chunked swizzle (m204): contiguous chunks of work per XCD
__device__ __forceinline__ int xcd_swizzle(int orig, int nwg) {
  int q8 = nwg >> 3, r8 = nwg & 7, xcd = orig & 7, base = orig >> 3;
  return (xcd < r8 ? xcd * (q8 + 1) : r8 * (q8 + 1) + (xcd - r8) * q8) + base;
}

// ---------------- fused f32 -> f16 conversion for 8 tensors ----------------
__global__ __launch_bounds__(256) void conv_all(
    const float* __restrict__ q, const float* __restrict__ k,
    const float* __restrict__ wqa, const float* __restrict__ wqb,
    const float* __restrict__ wkva, const float* __restrict__ wo,
    const float* __restrict__ fcc, const float* __restrict__ fcp,
    _Float16* q16, _Float16* k16, _Float16* wqa16, _Float16* wqb16,
    _Float16* wkva16, _Float16* wo16, _Float16* fcc16, _Float16* fcp16)
{
  size_t i = (size_t)blockIdx.x * 256 + threadIdx.x;  // half8-chunk index
  const float* in; _Float16* out; size_t off;
  if      (i < 1048576) { in = q;    out = q16;    off = i; }
  else if (i < 2097152) { in = k;    out = k16;    off = i - 1048576; }
  else if (i < 2490368) { in = wqa;  out = wqa16;  off = i - 2097152; }
  else if (i < 3080192) { in = wqb;  out = wqb16;  off = i - 2490368; }
  else if (i < 3227648) { in = wkva; out = wkva16; off = i - 3080192; }
  else if (i < 3751936) { in = wo;   out = wo16;   off = i - 3227648; }
  else if (i < 3760128) { in = fcc;  out = fcc16;  off = i - 3751936; }
  else                  { in = fcp;  out = fcp16;  off = i - 3760128; }
  float4 a = ((const float4*)in)[2 * off];
  float4 b = ((const float4*)in)[2 * off + 1];
  half8 h = {(_Float16)a.x, (_Float16)a.y, (_Float16)a.z, (_Float16)a.w,
             (_Float16)b.x, (_Float16)b.y, (_Float16)b.z, (_Float16)b.w};
  *(half8*)(out + 8 * off) = h;
}

// ------- f16 MFMA GEMM, m97-structure: global_load_lds + XOR-swizzled LDS -------
// C = A @ B^T (+bias). 128x128 tile, BK=64, 4 waves, single-buffered 32KB LDS.
template<bool OUT16, bool NB, bool BIAS>
__global__ __launch_bounds__(256) void gemm16(
    const _Float16* __restrict__ A, const _Float16* __restrict__ Bm,
    const float* __restrict__ bias, float* __restrict__ Cf,
    _Float16* __restrict__ Ch, int N, int K, int lda, int ldb, int ldc)
{
  __shared__ __align__(16) _Float16 Asl[128 * 64];
  __shared__ __align__(16) _Float16 Bsl[128 * 64];
  const int gx = gridDim.x;
  const int nwg = gx * gridDim.y;
  const int f = xcd_swizzle(blockIdx.y * gx + blockIdx.x, nwg);
  const int bm = (f / gx) * 128, bn = (f % gx) * 128;
  const int tid = threadIdx.x;
  const int w = tid >> 6, lane = tid & 63, l15 = lane & 15, g = lane >> 4;
  const int wm = (w >> 1) * 64, wn = (w & 1) * 64;
  const int srow = w * 32 + (lane >> 3);
  const int sch  = (lane & 7) ^ (lane >> 3);   // global chunk this lane fetches
  floatx4 acc[4][4];
  #pragma unroll
  for (int i = 0; i < 4; ++i)
    #pragma unroll
    for (int j = 0; j < 4; ++j) acc[i][j] = (floatx4){0.f, 0.f, 0.f, 0.f};
  for (int k0 = 0; k0 < K; k0 += 64) {
    __syncthreads();
    #pragma unroll
    for (int i = 0; i < 4; ++i)
      gload16(A + (size_t)(bm + srow + i * 8) * lda + k0 + sch * 8,
              Asl + (w * 256 + i * 64) * 8);
    #pragma unroll
    for (int i = 0; i < 4; ++i)
      gload16(Bm + (size_t)(bn + srow + i * 8) * ldb + k0 + sch * 8,
              Bsl + (w * 256 + i * 64) * 8);
    __syncthreads();
    #pragma unroll
    for (int kk = 0; kk < 2; ++kk) {
      half8 af[4], bf[4];
      const int sw = ((kk * 4 + g) ^ (l15 & 7)) * 8;  // swizzled read chunk
      #pragma unroll
      for (int i = 0; i < 4; ++i) {
        af[i] = *(const half8*)&Asl[(wm + i * 16 + l15) * 64 + sw];
        bf[i] = *(const half8*)&Bsl[(wn + i * 16 + l15) * 64 + sw];
      }
      #pragma unroll
      for (int i = 0; i < 4; ++i)
        #pragma unroll
        for (int j = 0; j < 4; ++j)
          acc[i][j] = MFMA16(af[i], bf[j], acc[i][j]);
    }
  }
  #pragma unroll
  for (int i = 0; i < 4; ++i)
    #pragma unroll
    for (int j = 0; j < 4; ++j)
      #pragma unroll
      for (int r = 0; r < 4; ++r) {
        int row = bm + wm + i * 16 + g * 4 + r;
        int col = bn + wn + j * 16 + l15;
        if (!NB || col < N) {
          float v = acc[i][j][r];
          if (BIAS) v += bias[col];
          if (OUT16) Ch[(size_t)row * ldc + col] = (_Float16)v;
          else       Cf[(size_t)row * ldc + col] = v;
        }
      }
}

// ---------------- row LayerNorm (templated in/out) ----------------
template<typename TIN, bool OUT16>
__global__ __launch_bounds__(256) void ln_rows(
    const TIN* __restrict__ in, float* __restrict__ outf, _Float16* __restrict__ outh,
    const float* __restrict__ g, const float* __restrict__ bb,
    int L, int ldin, int ldout)
{
  const int row = blockIdx.x;
  const TIN* x = in + (size_t)row * ldin;
  float s = 0.f, s2 = 0.f;
  for (int i = threadIdx.x; i < L; i += 256) {
    float v = (float)x[i]; s += v; s2 += v * v;
  }
  #pragma unroll
  for (int off = 32; off; off >>= 1) {
    s  += __shfl_xor(s, off, 64);
    s2 += __shfl_xor(s2, off, 64);
  }
  __shared__ float rs[4], rs2[4];
  int lane = threadIdx.x & 63, w = threadIdx.x >> 6;
  if (lane == 0) { rs[w] = s; rs2[w] = s2; }
  __syncthreads();
  s  = rs[0] + rs[1] + rs[2] + rs[3];
  s2 = rs2[0] + rs2[1] + rs2[2] + rs2[3];
  float mean = s / L;
  float var = s2 / L - mean * mean;
  float inv = rsqrtf(var + 1e-5f);
  for (int i = threadIdx.x; i < L; i += 256) {
    float v = ((float)x[i] - mean) * inv * g[i] + bb[i];
    if (OUT16) outh[(size_t)row * ldout + i] = (_Float16)v;
    else       outf[(size_t)row * ldout + i] = v;
  }
}

// ------- rope + normalize q_pe in place (f16), fold ps*scale -------
__global__ __launch_bounds__(64) void rope_q16(_Float16* __restrict__ qb,
                                               const float* __restrict__ ps_ptr)
{
  const int idx = blockIdx.x;
  const int h = idx & (H_ - 1);
  const int row = idx >> 4;
  const int s = row & (S_ - 1);
  _Float16* p = qb + (size_t)row * 3072 + h * 192 + NOPE_;
  const int j = threadIdx.x;
  float o1 = 0.f, o2 = 0.f;
  if (j < 32) {
    float invf = expf(-(float)j * (LN1E4 / 32.f));
    float ang = (float)(S_ - 1 + s) * invf;
    float sn, cs; sincosf(ang, &sn, &cs);
    float x1 = (float)p[2 * j], x2 = (float)p[2 * j + 1];
    o1 = x1 * cs - x2 * sn;
    o2 = x1 * sn + x2 * cs;
  }
  float ss = o1 * o1 + o2 * o2;
  #pragma unroll
  for (int off = 32; off; off >>= 1) ss += __shfl_xor(ss, off, 64);
  float inv = ps_ptr[0] * SCALE_ / fmaxf(sqrtf(ss), 1e-12f);
  if (j < 32) {
    p[2 * j]     = (_Float16)(o1 * inv);
    p[2 * j + 1] = (_Float16)(o2 * inv);
  }
}

// ------- rope + normalize k_pe (odd rows) -> keff[b][h][t][128..192] all h -------
__global__ __launch_bounds__(64) void rope_k16(
    const _Float16* __restrict__ kvf16, _Float16* __restrict__ keff)
{
  const int t = blockIdx.x, b = blockIdx.y;
  const int srow = 2 * t + 1;
  const _Float16* p = kvf16 + ((size_t)(b * S_ + srow)) * 576 + C_;
  const int j = threadIdx.x;
  float o1 = 0.f, o2 = 0.f;
  if (j < 32) {
    float invf = expf(-(float)j * (LN1E4 / 32.f));
    float ang = (float)(S_ - 1 + srow) * invf;
    float sn, cs; sincosf(ang, &sn, &cs);
    float x1 = (float)p[2 * j], x2 = (float)p[2 * j + 1];
    o1 = x1 * cs - x2 * sn;
    o2 = x1 * sn + x2 * cs;
  }
  float ss = o1 * o1 + o2 * o2;
  #pragma unroll
  for (int off = 32; off; off >>= 1) ss += __shfl_xor(ss, off, 64);
  float nrm = fmaxf(sqrtf(ss), 1e-12f);
  if (j < 32) {
    _Float16 h1 = (_Float16)(o1 / nrm), h2 = (_Float16)(o2 / nrm);
    #pragma unroll
    for (int h = 0; h < H_; ++h) {
      _Float16* o = keff + ((size_t)((b * H_ + h) * T_) + t) * 192 + NOPE_;
      o[2 * j] = h1; o[2 * j + 1] = h2;
    }
  }
}

// ---------------- sinusoidal PE table (f16) ----------------
__global__ __launch_bounds__(256) void pe16(_Float16* __restrict__ Cpe16)
{
  const int t = blockIdx.x;
  const int i = threadIdx.x;
  float dv = expf(-(float)(2 * i) * (LN1E4 / 512.f));
  float ang = (float)t * dv;
  float sn, cs; sincosf(ang, &sn, &cs);
  Cpe16[(size_t)t * C_ + 2 * i]     = (_Float16)sn;
  Cpe16[(size_t)t * C_ + 2 * i + 1] = (_Float16)cs;
}

// ---------------- gate: pkv16[b][t] = w0*kvn[2t] + w1*kvn[2t+1] (all f16 in) ----------------
__global__ __launch_bounds__(64) void gate_kernel(
    const _Float16* __restrict__ C2, const _Float16* __restrict__ P2,
    const _Float16* __restrict__ kvn16, _Float16* __restrict__ pkv16)
{
  const int t = blockIdx.x, b = blockIdx.y;
  const int j = threadIdx.x;
  const _Float16* c2 = C2 + (size_t)t * 128;
  const _Float16* p0 = P2 + ((size_t)(b * S_ + 2 * t)) * 128;
  const _Float16* p1 = p0 + 128;
  float d0 = (float)c2[j] * (float)p0[j] + (float)c2[j + 64] * (float)p0[j + 64];
  float d1 = (float)c2[j] * (float)p1[j] + (float)c2[j + 64] * (float)p1[j + 64];
  #pragma unroll
  for (int off = 32; off; off >>= 1) {
    d0 += __shfl_xor(d0, off, 64);
    d1 += __shfl_xor(d1, off, 64);
  }
  float w0 = 1.f / (1.f + expf(-d0));
  float w1 = 1.f / (1.f + expf(-d1));
  const _Float16* k0 = kvn16 + ((size_t)(b * S_ + 2 * t)) * C_;
  const _Float16* k1 = k0 + C_;
  _Float16* o = pkv16 + ((size_t)(b * T_ + t)) * C_;
  #pragma unroll
  for (int it = 0; it < 2; ++it) {
    int c = j * 4 + it * 256;
    #pragma unroll
    for (int u = 0; u < 4; ++u)
      o[c + u] = (_Float16)(w0 * (float)k0[c + u] + w1 * (float)k1[c + u]);
  }
}

// ---- conv_wkvb: W1c[h][d][c] = wkvb[h][d][c]*SCALE (f16); W2c = wkvb[h][128+d][c] ----
__global__ __launch_bounds__(256) void conv_wkvb(
    const float* __restrict__ wkvb, _Float16* __restrict__ W1c,
    _Float16* __restrict__ W2c)
{
  int i = blockIdx.x * 256 + threadIdx.x;
  const int half = 16 * 128 * 512;
  if (i < half) {
    int c = i & 511, d = (i >> 9) & 127, h = i >> 16;
    W1c[i] = (_Float16)(wkvb[((size_t)(h * 256 + d)) * 512 + c] * SCALE_);
  } else {
    int j = i - half;
    int c = j & 511, d = (j >> 9) & 127, h = j >> 16;
    W2c[j] = (_Float16)wkvb[((size_t)(h * 256 + 128 + d)) * 512 + c];
  }
}

// ---- prep_kv: khead = pkv @ W1c^T -> keff[..][0:128]; vhead^T -> vT[b][h][d][t] ----
__global__ __launch_bounds__(256) void prep_kv(
    const _Float16* __restrict__ pkv16, const _Float16* __restrict__ W1c,
    const _Float16* __restrict__ W2c, _Float16* __restrict__ keff,
    _Float16* __restrict__ vT)
{
  const int b = blockIdx.z, h = blockIdx.y;
  const int tid = threadIdx.x, w = tid >> 6, lane = tid & 63;
  const int l15 = lane & 15, g = lane >> 4;
  const int t0 = blockIdx.x * 64 + w * 16;
  half8 ap[16];
  #pragma unroll
  for (int kk = 0; kk < 16; ++kk)
    ap[kk] = *(const half8*)(pkv16 + ((size_t)(b * T_) + t0 + l15) * 512 + kk * 32 + g * 8);
  floatx4 acc[8];
  #pragma unroll
  for (int i = 0; i < 8; ++i) acc[i] = (floatx4){0.f, 0.f, 0.f, 0.f};
  #pragma unroll
  for (int kk = 0; kk < 16; ++kk)
    #pragma unroll
    for (int cc = 0; cc < 8; ++cc)
      acc[cc] = MFMA16(ap[kk],
          *(const half8*)(W1c + ((size_t)(h * 128 + cc * 16 + l15)) * 512 + kk * 32 + g * 8),
          acc[cc]);
  #pragma unroll
  for (int cc = 0; cc < 8; ++cc)
    #pragma unroll
    for (int r = 0; r < 4; ++r)
      keff[((size_t)((b * H_ + h) * T_) + t0 + g * 4 + r) * 192 + cc * 16 + l15] =
          (_Float16)acc[cc][r];
  #pragma unroll
  for (int i = 0; i < 8; ++i) acc[i] = (floatx4){0.f, 0.f, 0.f, 0.f};
  #pragma unroll
  for (int kk = 0; kk < 16; ++kk)
    #pragma unroll
    for (int cc = 0; cc < 8; ++cc)
      acc[cc] = MFMA16(ap[kk],
          *(const half8*)(W2c + ((size_t)(h * 128 + cc * 16 + l15)) * 512 + kk * 32 + g * 8),
          acc[cc]);
  #pragma unroll
  for (int cc = 0; cc < 8; ++cc)
    #pragma unroll
    for (int r = 0; r < 4; ++r)
      vT[((size_t)((b * H_ + h) * 128) + cc * 16 + l15) * T_ + t0 + g * 4 + r] =
          (_Float16)acc[cc][r];
}

// ------- flash attention: d_qk=192, d_v=128; async-staged K/V, setprio, defer-max -------
// grid = 1024 flat blocks (XCD-chunk-swizzled), 4 waves x 16 q-rows.
__global__ __launch_bounds__(256, 2) void attn_flash(
    const _Float16* __restrict__ qb16, const _Float16* __restrict__ keff,
    const _Float16* __restrict__ vT, _Float16* __restrict__ x216)
{
  __shared__ __align__(16) _Float16 K_lds[64 * 200];  // 25.6 KB
  __shared__ __align__(16) _Float16 V_lds[128 * 72];  // 18.4 KB
  __shared__ __align__(16) _Float16 P_lds[64 * 72];   // 9.2 KB
  const int f = xcd_swizzle(blockIdx.x, 1024);
  const int st = f & 31, h = (f >> 5) & 15, b = f >> 9;
  const int tid = threadIdx.x, w = tid >> 6, lane = tid & 63;
  const int l15 = lane & 15, g = lane >> 4;
  const int rq = b * S_ + st * 64 + w * 16;
  const _Float16* qrow = qb16 + (size_t)(rq + l15) * 3072 + h * 192;
  half8 qA[6];
  #pragma unroll
  for (int kk = 0; kk < 6; ++kk) qA[kk] = *(const half8*)(qrow + kk * 32 + g * 8);
  floatx4 O[8];
  #pragma unroll
  for (int i = 0; i < 8; ++i) O[i] = (floatx4){0.f, 0.f, 0.f, 0.f};
  float m[4] = {-3e38f, -3e38f, -3e38f, -3e38f};
  float l[4] = {0.f, 0.f, 0.f, 0.f};
  const _Float16* kb = keff + (size_t)(b * H_ + h) * T_ * 192;
  const _Float16* vb = vT   + (size_t)(b * H_ + h) * 128 * T_;

  // staging lane assignments
  const int krow[6] = {(tid) / 24, (tid + 256) / 24, (tid + 512) / 24,
                       (tid + 768) / 24, (tid + 1024) / 24, (tid + 1280) / 24};
  const int kcol[6] = {(tid % 24) * 8, ((tid + 256) % 24) * 8, ((tid + 512) % 24) * 8,
                       ((tid + 768) % 24) * 8, ((tid + 1024) % 24) * 8, ((tid + 1280) % 24) * 8};
  half8 kreg[6], vreg[4];

  // prologue: stage tile 0
  #pragma unroll
  for (int p = 0; p < 6; ++p)
    kreg[p] = *(const half8*)(kb + (size_t)krow[p] * 192 + kcol[p]);
  #pragma unroll
  for (int p = 0; p < 4; ++p) {
    int c = tid + p * 256;
    vreg[p] = *(const half8*)(vb + (size_t)(c >> 3) * T_ + (c & 7) * 8);
  }
  #pragma unroll
  for (int p = 0; p < 6; ++p)
    *(half8*)&K_lds[krow[p] * 200 + kcol[p]] = kreg[p];
  #pragma unroll
  for (int p = 0; p < 4; ++p) {
    int c = tid + p * 256;
    *(half8*)&V_lds[(c >> 3) * 72 + (c & 7) * 8] = vreg[p];
  }
  __syncthreads();

  for (int kt = 0; kt < 16; ++kt) {
    // issue next tile's global loads (latency hides under compute below)
    if (kt < 15) {
      const int t1 = (kt + 1) * 64;
      #pragma unroll
      for (int p = 0; p < 6; ++p)
        kreg[p] = *(const half8*)(kb + (size_t)(t1 + krow[p]) * 192 + kcol[p]);
      #pragma unroll
      for (int p = 0; p < 4; ++p) {
        int c = tid + p * 256;
        vreg[p] = *(const half8*)(vb + (size_t)(c >> 3) * T_ + t1 + (c & 7) * 8);
      }
    }
    // scores
    floatx4 sc[4];
    #pragma unroll
    for (int i = 0; i < 4; ++i) sc[i] = (floatx4){0.f, 0.f, 0.f, 0.f};
    __builtin_amdgcn_s_setprio(1);
    #pragma unroll
    for (int kk = 0; kk < 6; ++kk)
      #pragma unroll
      for (int ct = 0; ct < 4; ++ct)
        sc[ct] = MFMA16(qA[kk],
            *(const half8*)&K_lds[(ct * 16 + l15) * 200 + kk * 32 + g * 8], sc[ct]);
    __builtin_amdgcn_s_setprio(0);
    // online softmax with defer-max (THR=8)
    float pm[4], rs[4];
    #pragma unroll
    for (int r = 0; r < 4; ++r)
      pm[r] = fmaxf(fmaxf(sc[0][r], sc[1][r]), fmaxf(sc[2][r], sc[3][r]));
    #pragma unroll
    for (int off = 1; off < 16; off <<= 1)
      #pragma unroll
      for (int r = 0; r < 4; ++r) pm[r] = fmaxf(pm[r], __shfl_xor(pm[r], off, 64));
    int ok = (pm[0] <= m[0] + 8.f) & (pm[1] <= m[1] + 8.f) &
             (pm[2] <= m[2] + 8.f) & (pm[3] <= m[3] + 8.f);
    if (!__all(ok)) {
      #pragma unroll
      for (int r = 0; r < 4; ++r) {
        float mn = fmaxf(m[r], pm[r]);
        float sf = __expf(m[r] - mn);
        m[r] = mn; l[r] *= sf;
        #pragma unroll
        for (int cc = 0; cc < 8; ++cc) O[cc][r] *= sf;
      }
    }
    #pragma unroll
    for (int r = 0; r < 4; ++r) rs[r] = 0.f;
    #pragma unroll
    for (int ct = 0; ct < 4; ++ct)
      #pragma unroll
      for (int r = 0; r < 4; ++r) {
        float e = __expf(sc[ct][r] - m[r]);
        sc[ct][r] = e; rs[r] += e;
      }
    #pragma unroll
    for (int off = 1; off < 16; off <<= 1)
      #pragma unroll
      for (int r = 0; r < 4; ++r) rs[r] += __shfl_xor(rs[r], off, 64);
    #pragma unroll
    for (int r = 0; r < 4; ++r) l[r] += rs[r];
    // P -> LDS (wave-private rows; no barrier needed)
    #pragma unroll
    for (int ct = 0; ct < 4; ++ct)
      #pragma unroll
      for (int r = 0; r < 4; ++r)
        P_lds[(w * 16 + g * 4 + r) * 72 + ct * 16 + l15] = (_Float16)sc[ct][r];
    // PV
    __builtin_amdgcn_s_setprio(1);
    #pragma unroll
    for (int kc = 0; kc < 2; ++kc) {
      half8 pa = *(const half8*)&P_lds[(w * 16 + l15) * 72 + kc * 32 + g * 8];
      #pragma unroll
      for (int cc = 0; cc < 8; ++cc)
        O[cc] = MFMA16(pa,
            *(const half8*)&V_lds[(cc * 16 + l15) * 72 + kc * 32 + g * 8], O[cc]);
    }
    __builtin_amdgcn_s_setprio(0);
    // commit next tile to LDS
    if (kt < 15) {
      __syncthreads();   // all waves done reading current tile
      #pragma unroll
      for (int p = 0; p < 6; ++p)
        *(half8*)&K_lds[krow[p] * 200 + kcol[p]] = kreg[p];
      #pragma unroll
      for (int p = 0; p < 4; ++p) {
        int c = tid + p * 256;
        *(half8*)&V_lds[(c >> 3) * 72 + (c & 7) * 8] = vreg[p];
      }
      __syncthreads();   // next tile visible
    }
  }
  float il[4] = {1.f / l[0], 1.f / l[1], 1.f / l[2], 1.f / l[3]};
  #pragma unroll
  for (int cc = 0; cc < 8; ++cc)
    #pragma unroll
    for (int r = 0; r < 4; ++r)
      x216[(size_t)(rq + g * 4 + r) * 2048 + h * 128 + cc * 16 + l15] =
          (_Float16)(O[cc][r] * il[r]);
}

extern "C" void kernel_launch(void* const* d_in, const int* in_sizes, int n_in,
                              void* d_out, int out_size, void* d_ws, size_t ws_size,
                              hipStream_t stream)
{
  (void)in_sizes; (void)n_in; (void)out_size; (void)ws_size;
  const float* query  = (const float*)d_in[0];
  const float* key    = (const float*)d_in[1];
  const float* wq_a   = (const float*)d_in[3];
  const float* q_ln_g = (const float*)d_in[4];
  const float* q_ln_b = (const float*)d_in[5];
  const float* wq_b   = (const float*)d_in[6];
  const float* wkv_a  = (const float*)d_in[7];
  const float* kv_ln_g= (const float*)d_in[8];
  const float* kv_ln_b= (const float*)d_in[9];
  const float* wkvb   = (const float*)d_in[10];
  const float* wo     = (const float*)d_in[11];
  const float* fc_c_w = (const float*)d_in[12];
  const float* fc_c_b = (const float*)d_in[13];
  const float* fc_p_w = (const float*)d_in[14];
  const float* fc_p_b = (const float*)d_in[15];
  const float* ps     = (const float*)d_in[16];
  float* out = (float*)d_out;

  const int M = B_ * S_; // 4096
  // ---- workspace layout (halves), ~108 MB, heavy aliasing ----
  _Float16* hws   = (_Float16*)d_ws;
  _Float16* q16   = hws;                      // 8,388,608   (later: x216)
  _Float16* key16 = q16   + (size_t)8388608;  // 8,388,608   (later: keff 6,291,456)
  _Float16* wqa16 = key16 + (size_t)8388608;  // 3,145,728   (later: W1c|W2c 2,097,152)
  _Float16* wqb16 = wqa16 + (size_t)3145728;  // 4,718,592   (later: Cpe16/C2h/P2h)
  _Float16* wkva16= wqb16 + (size_t)4718592;  // 1,179,648   (later: pkv16 1,048,576)
  _Float16* wo16  = wkva16+ (size_t)1179648;  // 4,194,304
  _Float16* ql16  = wo16  + (size_t)4194304;  // 6,291,456   (later: vT 4,194,304)
  _Float16* qb16  = ql16  + (size_t)6291456;  // 12,582,912
  _Float16* kvf16 = qb16  + (size_t)12582912; // 2,359,296
  _Float16* kvn16 = kvf16 + (size_t)2359296;  // 2,097,152
  _Float16* fcc16 = kvn16 + (size_t)2097152;  // 65,536
  _Float16* fcp16 = fcc16 + (size_t)65536;    // 65,536
  // aliases
  _Float16* x216  = q16;
  _Float16* keff  = key16;
  _Float16* W1c   = wqa16;
  _Float16* W2c   = W1c + (size_t)1048576;
  _Float16* Cpe16 = wqb16;
  _Float16* C2h   = Cpe16 + (size_t)T_ * C_;
  _Float16* P2h   = C2h + (size_t)T_ * 128;
  _Float16* pkv16 = wkva16;
  _Float16* vT    = ql16;
  float*    qlp   = out;  // d_out as fp32 scratch (dead after LN)

  // 0. all f32->f16 conversions in one kernel
  conv_all<<<14720, 256, 0, stream>>>(query, key, wq_a, wq_b, wkv_a, wo, fc_c_w, fc_p_w,
                                      q16, key16, wqa16, wqb16, wkva16, wo16, fcc16, fcp16);
  // 1. qlp = query @ wq_a^T (fp32 out in d_out)
  gemm16<false,false,false><<<dim3(QR_/128, M/128), 256, 0, stream>>>(
      q16, wqa16, nullptr, qlp, nullptr, QR_, E_, E_, E_, QR_);
  // (wqa16 dead -> W1c/W2c)
  conv_wkvb<<<8192, 256, 0, stream>>>(wkvb, W1c, W2c);
  // 2. LN -> ql16
  ln_rows<float,true><<<M, 256, 0, stream>>>(qlp, nullptr, ql16, q_ln_g, q_ln_b,
                                             QR_, QR_, QR_);
  // 3. qb16 = ql16 @ wq_b^T
  gemm16<true,false,false><<<dim3(3072/128, M/128), 256, 0, stream>>>(
      ql16, wqb16, nullptr, nullptr, qb16, 3072, QR_, QR_, QR_, 3072);
  // 4. rope q_pe in place
  rope_q16<<<M * H_, 64, 0, stream>>>(qb16, ps);
  // 5. kvf16 = key @ wkv_a^T (N=576, bounds-checked writes)
  gemm16<true,true,false><<<dim3(5, M/128), 256, 0, stream>>>(
      key16, wkva16, nullptr, nullptr, kvf16, 576, E_, E_, E_, 576);
  // 6. kvn16 = LN(kvf16[:, :512])
  ln_rows<_Float16,true><<<M, 256, 0, stream>>>(kvf16, nullptr, kvn16, kv_ln_g, kv_ln_b,
                                                C_, 576, C_);
  // 7. kpe -> keff[...,128:192] (key16 dead)
  rope_k16<<<dim3(T_, B_), 64, 0, stream>>>(kvf16, keff);
  // 8. PE table f16 (wqb16 dead)
  pe16<<<T_, 256, 0, stream>>>(Cpe16);
  // 9. C2h = Cpe16 @ fcc16^T + fc_c_b
  gemm16<true,false,true><<<dim3(1, T_/128), 256, 0, stream>>>(
      Cpe16, fcc16, fc_c_b, nullptr, C2h, 128, C_, C_, C_, 128);
  // 10. P2h = kvn16 @ fcp16^T + fc_p_b
  gemm16<true,false,true><<<dim3(1, M/128), 256, 0, stream>>>(
      kvn16, fcp16, fc_p_b, nullptr, P2h, 128, C_, C_, C_, 128);
  // 11. gate -> pkv16 (wkva16 dead)
  gate_kernel<<<dim3(T_, B_), 64, 0, stream>>>(C2h, P2h, kvn16, pkv16);
  // 12. khead/vhead -> keff[...,0:128], vT (ql16 dead)
  prep_kv<<<dim3(T_/64, H_, B_), 256, 0, stream>>>(pkv16, W1c, W2c, keff, vT);
  // 13. flash attention (1 q-tile/block, async-staged) -> x216 (q16 dead)
  attn_flash<<<dim3(1024), 256, 0, stream>>>(qb16, keff, vT, x216);
  // 14. out = x216 @ wo16^T (fp32 out)
  gemm16<false,false,false><<<dim3(E_/128, M/128), 256, 0, stream>>>(
      x216, wo16, nullptr, out, nullptr, E_, E_, E_, E_, E_);
}

// Round 7
// 395.513 us; speedup vs baseline: 18.9408x; 1.1699x over previous
//
#include <hip/hip_runtime.h>
#include <math.h>

#define S_ 2048
#define B_ 2
#define H_ 16
#define E_ 2048
#define QR_ 1536
#define NOPE_ 128
#define ROPE_ 64
#define C_ 512
#define VH_ 128
#define T_ 1024
#define LN1E4 9.210340371976184f
#define SCALE_ 0.07216878364870323f  // 192^-0.5

typedef _Float16 half8 __attribute__((ext_vector_type(8)));
typedef _Float16 half4 __attribute__((ext_vector_type(4)));
typedef float floatx4 __attribute__((ext_vector_type(4)));
#define MFMA16(a, b, c) __builtin_amdgcn_mfma_f32_16x16x32_f16(a, b, c, 0, 0, 0)

__device__ __forceinline__ void gload16(const _Float16* g, _Float16* l) {
  __builtin_amdgcn_global_load_lds(
      (__attribute__((address_space(1))) const void*)g,
      (__attribute__((address_space(3))) void*)l, 16, 0, 0);
}

// bijective XCD-chunked swizzle (m204): contiguous chunks of work per XCD
__device__ __forceinline__ int xcd_swizzle(int orig, int nwg) {
  int q8 = nwg >> 3, r8 = nwg & 7, xcd = orig & 7, base = orig >> 3;
  return (xcd < r8 ? xcd * (q8 + 1) : r8 * (q8 + 1) + (xcd - r8) * q8) + base;
}

// ---------------- fused f32 -> f16 conversion for 8 tensors ----------------
__global__ __launch_bounds__(256) void conv_all(
    const float* __restrict__ q, const float* __restrict__ k,
    const float* __restrict__ wqa, const float* __restrict__ wqb,
    const float* __restrict__ wkva, const float* __restrict__ wo,
    const float* __restrict__ fcc, const float* __restrict__ fcp,
    _Float16* q16, _Float16* k16, _Float16* wqa16, _Float16* wqb16,
    _Float16* wkva16, _Float16* wo16, _Float16* fcc16, _Float16* fcp16)
{
  size_t i = (size_t)blockIdx.x * 256 + threadIdx.x;  // half8-chunk index
  const float* in; _Float16* out; size_t off;
  if      (i < 1048576) { in = q;    out = q16;    off = i; }
  else if (i < 2097152) { in = k;    out = k16;    off = i - 1048576; }
  else if (i < 2490368) { in = wqa;  out = wqa16;  off = i - 2097152; }
  else if (i < 3080192) { in = wqb;  out = wqb16;  off = i - 2490368; }
  else if (i < 3227648) { in = wkva; out = wkva16; off = i - 3080192; }
  else if (i < 3751936) { in = wo;   out = wo16;   off = i - 3227648; }
  else if (i < 3760128) { in = fcc;  out = fcc16;  off = i - 3751936; }
  else                  { in = fcp;  out = fcp16;  off = i - 3760128; }
  float4 a = ((const float4*)in)[2 * off];
  float4 b = ((const float4*)in)[2 * off + 1];
  half8 h = {(_Float16)a.x, (_Float16)a.y, (_Float16)a.z, (_Float16)a.w,
             (_Float16)b.x, (_Float16)b.y, (_Float16)b.z, (_Float16)b.w};
  *(half8*)(out + 8 * off) = h;
}

// ------- f16 MFMA GEMM: global_load_lds + XOR swizzle + DOUBLE-BUFFER counted vmcnt -------
// C = A @ B^T (+bias). 128x128 tile, BK=64, 4 waves, 2x32KB LDS, 8-deep load pipeline.
// grid.z batching: per-z offsets decomposed as z=(zb<<4)|zh.
template<bool OUT16, bool NB, bool BIAS, bool TRANSC>
__global__ __launch_bounds__(256) void gemm16(
    const _Float16* __restrict__ A, const _Float16* __restrict__ Bm,
    const float* __restrict__ bias, float* __restrict__ Cf,
    _Float16* __restrict__ Ch, int N, int K, int lda, int ldb, int ldc,
    long sAb, long sAh, long sBb, long sBh, long sCb, long sCh)
{
  __shared__ __align__(16) _Float16 Asl[2][128 * 64];
  __shared__ __align__(16) _Float16 Bsl[2][128 * 64];
  const int z = blockIdx.z, zb = z >> 4, zh = z & 15;
  A  += (size_t)zb * sAb + (size_t)zh * sAh;
  Bm += (size_t)zb * sBb + (size_t)zh * sBh;
  if (OUT16) Ch += (size_t)zb * sCb + (size_t)zh * sCh;
  else       Cf += (size_t)zb * sCb + (size_t)zh * sCh;
  const int gx = gridDim.x;
  const int nwg = gx * gridDim.y;
  const int f = xcd_swizzle(blockIdx.y * gx + blockIdx.x, nwg);
  const int bm = (f / gx) * 128, bn = (f % gx) * 128;
  const int tid = threadIdx.x;
  const int w = tid >> 6, lane = tid & 63, l15 = lane & 15, g = lane >> 4;
  const int wm = (w >> 1) * 64, wn = (w & 1) * 64;
  const int srow = w * 32 + (lane >> 3);
  const int sch  = (lane & 7) ^ (lane >> 3);   // inverse-swizzled global chunk
  floatx4 acc[4][4];
  #pragma unroll
  for (int i = 0; i < 4; ++i)
    #pragma unroll
    for (int j = 0; j < 4; ++j) acc[i][j] = (floatx4){0.f, 0.f, 0.f, 0.f};

  auto STAGE = [&](int buf, int k0) {
    _Float16* al = &Asl[buf][w * 2048];
    _Float16* bl = &Bsl[buf][w * 2048];
    #pragma unroll
    for (int i = 0; i < 4; ++i)
      gload16(A + (size_t)(bm + srow + i * 8) * lda + k0 + sch * 8, al + i * 512);
    #pragma unroll
    for (int i = 0; i < 4; ++i)
      gload16(Bm + (size_t)(bn + srow + i * 8) * ldb + k0 + sch * 8, bl + i * 512);
  };

  STAGE(0, 0);
  int cur = 0;
  const int nIter = K >> 6;
  for (int it = 0; it < nIter; ++it) {
    const bool pf = (it + 1 < nIter);
    if (pf) STAGE(cur ^ 1, (it + 1) << 6);      // 8 more in flight (16 total)
    if (pf) asm volatile("s_waitcnt vmcnt(8)" ::: "memory");   // wait cur's 8
    else    asm volatile("s_waitcnt vmcnt(0)" ::: "memory");
    __builtin_amdgcn_sched_barrier(0);
    __builtin_amdgcn_s_barrier();               // publish buf[cur]
    __builtin_amdgcn_sched_barrier(0);
    #pragma unroll
    for (int kk = 0; kk < 2; ++kk) {
      half8 af[4], bf[4];
      const int sw = ((kk * 4 + g) ^ (l15 & 7)) * 8;
      #pragma unroll
      for (int i = 0; i < 4; ++i) {
        af[i] = *(const half8*)&Asl[cur][(wm + i * 16 + l15) * 64 + sw];
        bf[i] = *(const half8*)&Bsl[cur][(wn + i * 16 + l15) * 64 + sw];
      }
      #pragma unroll
      for (int i = 0; i < 4; ++i)
        #pragma unroll
        for (int j = 0; j < 4; ++j)
          acc[i][j] = MFMA16(af[i], bf[j], acc[i][j]);
    }
    asm volatile("s_waitcnt lgkmcnt(0)" ::: "memory");
    __builtin_amdgcn_sched_barrier(0);
    __builtin_amdgcn_s_barrier();               // all reads of buf[cur] done
    __builtin_amdgcn_sched_barrier(0);
    cur ^= 1;
  }

  if (TRANSC) {
    // store C^T (f16): addr = col*ldc + row; 4 consecutive rows per lane
    #pragma unroll
    for (int i = 0; i < 4; ++i)
      #pragma unroll
      for (int j = 0; j < 4; ++j) {
        int row = bm + wm + i * 16 + g * 4;
        int col = bn + wn + j * 16 + l15;
        half4 v = {(_Float16)acc[i][j][0], (_Float16)acc[i][j][1],
                   (_Float16)acc[i][j][2], (_Float16)acc[i][j][3]};
        *(half4*)(Ch + (size_t)col * ldc + row) = v;
      }
  } else {
    #pragma unroll
    for (int i = 0; i < 4; ++i)
      #pragma unroll
      for (int j = 0; j < 4; ++j)
        #pragma unroll
        for (int r = 0; r < 4; ++r) {
          int row = bm + wm + i * 16 + g * 4 + r;
          int col = bn + wn + j * 16 + l15;
          if (!NB || col < N) {
            float v = acc[i][j][r];
            if (BIAS) v += bias[col];
            if (OUT16) Ch[(size_t)row * ldc + col] = (_Float16)v;
            else       Cf[(size_t)row * ldc + col] = v;
          }
        }
  }
}

// ---------------- row LayerNorm (templated in/out) ----------------
template<typename TIN, bool OUT16>
__global__ __launch_bounds__(256) void ln_rows(
    const TIN* __restrict__ in, float* __restrict__ outf, _Float16* __restrict__ outh,
    const float* __restrict__ g, const float* __restrict__ bb,
    int L, int ldin, int ldout)
{
  const int row = blockIdx.x;
  const TIN* x = in + (size_t)row * ldin;
  float s = 0.f, s2 = 0.f;
  for (int i = threadIdx.x; i < L; i += 256) {
    float v = (float)x[i]; s += v; s2 += v * v;
  }
  #pragma unroll
  for (int off = 32; off; off >>= 1) {
    s  += __shfl_xor(s, off, 64);
    s2 += __shfl_xor(s2, off, 64);
  }
  __shared__ float rs[4], rs2[4];
  int lane = threadIdx.x & 63, w = threadIdx.x >> 6;
  if (lane == 0) { rs[w] = s; rs2[w] = s2; }
  __syncthreads();
  s  = rs[0] + rs[1] + rs[2] + rs[3];
  s2 = rs2[0] + rs2[1] + rs2[2] + rs2[3];
  float mean = s / L;
  float var = s2 / L - mean * mean;
  float inv = rsqrtf(var + 1e-5f);
  for (int i = threadIdx.x; i < L; i += 256) {
    float v = ((float)x[i] - mean) * inv * g[i] + bb[i];
    if (OUT16) outh[(size_t)row * ldout + i] = (_Float16)v;
    else       outf[(size_t)row * ldout + i] = v;
  }
}

// ------- rope + normalize q_pe in place (f16), fold ps*scale -------
__global__ __launch_bounds__(64) void rope_q16(_Float16* __restrict__ qb,
                                               const float* __restrict__ ps_ptr)
{
  const int idx = blockIdx.x;
  const int h = idx & (H_ - 1);
  const int row = idx >> 4;
  const int s = row & (S_ - 1);
  _Float16* p = qb + (size_t)row * 3072 + h * 192 + NOPE_;
  const int j = threadIdx.x;
  float o1 = 0.f, o2 = 0.f;
  if (j < 32) {
    float invf = expf(-(float)j * (LN1E4 / 32.f));
    float ang = (float)(S_ - 1 + s) * invf;
    float sn, cs; sincosf(ang, &sn, &cs);
    float x1 = (float)p[2 * j], x2 = (float)p[2 * j + 1];
    o1 = x1 * cs - x2 * sn;
    o2 = x1 * sn + x2 * cs;
  }
  float ss = o1 * o1 + o2 * o2;
  #pragma unroll
  for (int off = 32; off; off >>= 1) ss += __shfl_xor(ss, off, 64);
  float inv = ps_ptr[0] * SCALE_ / fmaxf(sqrtf(ss), 1e-12f);
  if (j < 32) {
    p[2 * j]     = (_Float16)(o1 * inv);
    p[2 * j + 1] = (_Float16)(o2 * inv);
  }
}

// ------- rope + normalize k_pe (odd rows) -> keff[b][h][t][128..192] all h -------
__global__ __launch_bounds__(64) void rope_k16(
    const _Float16* __restrict__ kvf16, _Float16* __restrict__ keff)
{
  const int t = blockIdx.x, b = blockIdx.y;
  const int srow = 2 * t + 1;
  const _Float16* p = kvf16 + ((size_t)(b * S_ + srow)) * 576 + C_;
  const int j = threadIdx.x;
  float o1 = 0.f, o2 = 0.f;
  if (j < 32) {
    float invf = expf(-(float)j * (LN1E4 / 32.f));
    float ang = (float)(S_ - 1 + srow) * invf;
    float sn, cs; sincosf(ang, &sn, &cs);
    float x1 = (float)p[2 * j], x2 = (float)p[2 * j + 1];
    o1 = x1 * cs - x2 * sn;
    o2 = x1 * sn + x2 * cs;
  }
  float ss = o1 * o1 + o2 * o2;
  #pragma unroll
  for (int off = 32; off; off >>= 1) ss += __shfl_xor(ss, off, 64);
  float nrm = fmaxf(sqrtf(ss), 1e-12f);
  if (j < 32) {
    _Float16 h1 = (_Float16)(o1 / nrm), h2 = (_Float16)(o2 / nrm);
    #pragma unroll
    for (int h = 0; h < H_; ++h) {
      _Float16* o = keff + ((size_t)((b * H_ + h) * T_) + t) * 192 + NOPE_;
      o[2 * j] = h1; o[2 * j + 1] = h2;
    }
  }
}

// ---------------- sinusoidal PE table (f16) ----------------
__global__ __launch_bounds__(256) void pe16(_Float16* __restrict__ Cpe16)
{
  const int t = blockIdx.x;
  const int i = threadIdx.x;
  float dv = expf(-(float)(2 * i) * (LN1E4 / 512.f));
  float ang = (float)t * dv;
  float sn, cs; sincosf(ang, &sn, &cs);
  Cpe16[(size_t)t * C_ + 2 * i]     = (_Float16)sn;
  Cpe16[(size_t)t * C_ + 2 * i + 1] = (_Float16)cs;
}

// ---------------- gate: pkv16[b][t] = w0*kvn[2t] + w1*kvn[2t+1] (all f16 in) ----------------
__global__ __launch_bounds__(64) void gate_kernel(
    const _Float16* __restrict__ C2, const _Float16* __restrict__ P2,
    const _Float16* __restrict__ kvn16, _Float16* __restrict__ pkv16)
{
  const int t = blockIdx.x, b = blockIdx.y;
  const int j = threadIdx.x;
  const _Float16* c2 = C2 + (size_t)t * 128;
  const _Float16* p0 = P2 + ((size_t)(b * S_ + 2 * t)) * 128;
  const _Float16* p1 = p0 + 128;
  float d0 = (float)c2[j] * (float)p0[j] + (float)c2[j + 64] * (float)p0[j + 64];
  float d1 = (float)c2[j] * (float)p1[j] + (float)c2[j + 64] * (float)p1[j + 64];
  #pragma unroll
  for (int off = 32; off; off >>= 1) {
    d0 += __shfl_xor(d0, off, 64);
    d1 += __shfl_xor(d1, off, 64);
  }
  float w0 = 1.f / (1.f + expf(-d0));
  float w1 = 1.f / (1.f + expf(-d1));
  const _Float16* k0 = kvn16 + ((size_t)(b * S_ + 2 * t)) * C_;
  const _Float16* k1 = k0 + C_;
  _Float16* o = pkv16 + ((size_t)(b * T_ + t)) * C_;
  #pragma unroll
  for (int it = 0; it < 2; ++it) {
    int c = j * 4 + it * 256;
    #pragma unroll
    for (int u = 0; u < 4; ++u)
      o[c + u] = (_Float16)(w0 * (float)k0[c + u] + w1 * (float)k1[c + u]);
  }
}

// ---- conv_wkvb: W1c[h][d][c] = wkvb[h][d][c]*SCALE (f16); W2c = wkvb[h][128+d][c] ----
__global__ __launch_bounds__(256) void conv_wkvb(
    const float* __restrict__ wkvb, _Float16* __restrict__ W1c,
    _Float16* __restrict__ W2c)
{
  int i = blockIdx.x * 256 + threadIdx.x;
  const int half = 16 * 128 * 512;
  if (i < half) {
    int c = i & 511, d = (i >> 9) & 127, h = i >> 16;
    W1c[i] = (_Float16)(wkvb[((size_t)(h * 256 + d)) * 512 + c] * SCALE_);
  } else {
    int j = i - half;
    int c = j & 511, d = (j >> 9) & 127, h = j >> 16;
    W2c[j] = (_Float16)wkvb[((size_t)(h * 256 + 128 + d)) * 512 + c];
  }
}

// ------- flash attention: d_qk=192, d_v=128; async-staged K/V, setprio, defer-max -------
// grid = 1024 flat blocks (XCD-chunk-swizzled), 4 waves x 16 q-rows.
__global__ __launch_bounds__(256, 2) void attn_flash(
    const _Float16* __restrict__ qb16, const _Float16* __restrict__ keff,
    const _Float16* __restrict__ vT, _Float16* __restrict__ x216)
{
  __shared__ __align__(16) _Float16 K_lds[64 * 200];  // 25.6 KB
  __shared__ __align__(16) _Float16 V_lds[128 * 72];  // 18.4 KB
  __shared__ __align__(16) _Float16 P_lds[64 * 72];   // 9.2 KB
  const int f = xcd_swizzle(blockIdx.x, 1024);
  const int st = f & 31, h = (f >> 5) & 15, b = f >> 9;
  const int tid = threadIdx.x, w = tid >> 6, lane = tid & 63;
  const int l15 = lane & 15, g = lane >> 4;
  const int rq = b * S_ + st * 64 + w * 16;
  const _Float16* qrow = qb16 + (size_t)(rq + l15) * 3072 + h * 192;
  half8 qA[6];
  #pragma unroll
  for (int kk = 0; kk < 6; ++kk) qA[kk] = *(const half8*)(qrow + kk * 32 + g * 8);
  floatx4 O[8];
  #pragma unroll
  for (int i = 0; i < 8; ++i) O[i] = (floatx4){0.f, 0.f, 0.f, 0.f};
  float m[4] = {-3e38f, -3e38f, -3e38f, -3e38f};
  float l[4] = {0.f, 0.f, 0.f, 0.f};
  const _Float16* kb = keff + (size_t)(b * H_ + h) * T_ * 192;
  const _Float16* vb = vT   + (size_t)(b * H_ + h) * 128 * T_;

  const int krow[6] = {(tid) / 24, (tid + 256) / 24, (tid + 512) / 24,
                       (tid + 768) / 24, (tid + 1024) / 24, (tid + 1280) / 24};
  const int kcol[6] = {(tid % 24) * 8, ((tid + 256) % 24) * 8, ((tid + 512) % 24) * 8,
                       ((tid + 768) % 24) * 8, ((tid + 1024) % 24) * 8, ((tid + 1280) % 24) * 8};
  half8 kreg[6], vreg[4];

  #pragma unroll
  for (int p = 0; p < 6; ++p)
    kreg[p] = *(const half8*)(kb + (size_t)krow[p] * 192 + kcol[p]);
  #pragma unroll
  for (int p = 0; p < 4; ++p) {
    int c = tid + p * 256;
    vreg[p] = *(const half8*)(vb + (size_t)(c >> 3) * T_ + (c & 7) * 8);
  }
  #pragma unroll
  for (int p = 0; p < 6; ++p)
    *(half8*)&K_lds[krow[p] * 200 + kcol[p]] = kreg[p];
  #pragma unroll
  for (int p = 0; p < 4; ++p) {
    int c = tid + p * 256;
    *(half8*)&V_lds[(c >> 3) * 72 + (c & 7) * 8] = vreg[p];
  }
  __syncthreads();

  for (int kt = 0; kt < 16; ++kt) {
    if (kt < 15) {
      const int t1 = (kt + 1) * 64;
      #pragma unroll
      for (int p = 0; p < 6; ++p)
        kreg[p] = *(const half8*)(kb + (size_t)(t1 + krow[p]) * 192 + kcol[p]);
      #pragma unroll
      for (int p = 0; p < 4; ++p) {
        int c = tid + p * 256;
        vreg[p] = *(const half8*)(vb + (size_t)(c >> 3) * T_ + t1 + (c & 7) * 8);
      }
    }
    floatx4 sc[4];
    #pragma unroll
    for (int i = 0; i < 4; ++i) sc[i] = (floatx4){0.f, 0.f, 0.f, 0.f};
    __builtin_amdgcn_s_setprio(1);
    #pragma unroll
    for (int kk = 0; kk < 6; ++kk)
      #pragma unroll
      for (int ct = 0; ct < 4; ++ct)
        sc[ct] = MFMA16(qA[kk],
            *(const half8*)&K_lds[(ct * 16 + l15) * 200 + kk * 32 + g * 8], sc[ct]);
    __builtin_amdgcn_s_setprio(0);
    float pm[4], rs[4];
    #pragma unroll
    for (int r = 0; r < 4; ++r)
      pm[r] = fmaxf(fmaxf(sc[0][r], sc[1][r]), fmaxf(sc[2][r], sc[3][r]));
    #pragma unroll
    for (int off = 1; off < 16; off <<= 1)
      #pragma unroll
      for (int r = 0; r < 4; ++r) pm[r] = fmaxf(pm[r], __shfl_xor(pm[r], off, 64));
    int ok = (pm[0] <= m[0] + 8.f) & (pm[1] <= m[1] + 8.f) &
             (pm[2] <= m[2] + 8.f) & (pm[3] <= m[3] + 8.f);
    if (!__all(ok)) {
      #pragma unroll
      for (int r = 0; r < 4; ++r) {
        float mn = fmaxf(m[r], pm[r]);
        float sf = __expf(m[r] - mn);
        m[r] = mn; l[r] *= sf;
        #pragma unroll
        for (int cc = 0; cc < 8; ++cc) O[cc][r] *= sf;
      }
    }
    #pragma unroll
    for (int r = 0; r < 4; ++r) rs[r] = 0.f;
    #pragma unroll
    for (int ct = 0; ct < 4; ++ct)
      #pragma unroll
      for (int r = 0; r < 4; ++r) {
        float e = __expf(sc[ct][r] - m[r]);
        sc[ct][r] = e; rs[r] += e;
      }
    #pragma unroll
    for (int off = 1; off < 16; off <<= 1)
      #pragma unroll
      for (int r = 0; r < 4; ++r) rs[r] += __shfl_xor(rs[r], off, 64);
    #pragma unroll
    for (int r = 0; r < 4; ++r) l[r] += rs[r];
    #pragma unroll
    for (int ct = 0; ct < 4; ++ct)
      #pragma unroll
      for (int r = 0; r < 4; ++r)
        P_lds[(w * 16 + g * 4 + r) * 72 + ct * 16 + l15] = (_Float16)sc[ct][r];
    __builtin_amdgcn_s_setprio(1);
    #pragma unroll
    for (int kc = 0; kc < 2; ++kc) {
      half8 pa = *(const half8*)&P_lds[(w * 16 + l15) * 72 + kc * 32 + g * 8];
      #pragma unroll
      for (int cc = 0; cc < 8; ++cc)
        O[cc] = MFMA16(pa,
            *(const half8*)&V_lds[(cc * 16 + l15) * 72 + kc * 32 + g * 8], O[cc]);
    }
    __builtin_amdgcn_s_setprio(0);
    if (kt < 15) {
      __syncthreads();
      #pragma unroll
      for (int p = 0; p < 6; ++p)
        *(half8*)&K_lds[krow[p] * 200 + kcol[p]] = kreg[p];
      #pragma unroll
      for (int p = 0; p < 4; ++p) {
        int c = tid + p * 256;
        *(half8*)&V_lds[(c >> 3) * 72 + (c & 7) * 8] = vreg[p];
      }
      __syncthreads();
    }
  }
  float il[4] = {1.f / l[0], 1.f / l[1], 1.f / l[2], 1.f / l[3]};
  #pragma unroll
  for (int cc = 0; cc < 8; ++cc)
    #pragma unroll
    for (int r = 0; r < 4; ++r)
      x216[(size_t)(rq + g * 4 + r) * 2048 + h * 128 + cc * 16 + l15] =
          (_Float16)(O[cc][r] * il[r]);
}

extern "C" void kernel_launch(void* const* d_in, const int* in_sizes, int n_in,
                              void* d_out, int out_size, void* d_ws, size_t ws_size,
                              hipStream_t stream)
{
  (void)in_sizes; (void)n_in; (void)out_size; (void)ws_size;
  const float* query  = (const float*)d_in[0];
  const float* key    = (const float*)d_in[1];
  const float* wq_a   = (const float*)d_in[3];
  const float* q_ln_g = (const float*)d_in[4];
  const float* q_ln_b = (const float*)d_in[5];
  const float* wq_b   = (const float*)d_in[6];
  const float* wkv_a  = (const float*)d_in[7];
  const float* kv_ln_g= (const float*)d_in[8];
  const float* kv_ln_b= (const float*)d_in[9];
  const float* wkvb   = (const float*)d_in[10];
  const float* wo     = (const float*)d_in[11];
  const float* fc_c_w = (const float*)d_in[12];
  const float* fc_c_b = (const float*)d_in[13];
  const float* fc_p_w = (const float*)d_in[14];
  const float* fc_p_b = (const float*)d_in[15];
  const float* ps     = (const float*)d_in[16];
  float* out = (float*)d_out;

  const int M = B_ * S_; // 4096
  // ---- workspace layout (halves), ~108 MB, heavy aliasing ----
  _Float16* hws   = (_Float16*)d_ws;
  _Float16* q16   = hws;                      // 8,388,608   (later: x216)
  _Float16* key16 = q16   + (size_t)8388608;  // 8,388,608   (later: keff 6,291,456)
  _Float16* wqa16 = key16 + (size_t)8388608;  // 3,145,728   (later: W1c|W2c 2,097,152)
  _Float16* wqb16 = wqa16 + (size_t)3145728;  // 4,718,592   (later: Cpe16/C2h/P2h)
  _Float16* wkva16= wqb16 + (size_t)4718592;  // 1,179,648   (later: pkv16 1,048,576)
  _Float16* wo16  = wkva16+ (size_t)1179648;  // 4,194,304
  _Float16* ql16  = wo16  + (size_t)4194304;  // 6,291,456   (later: vT 4,194,304)
  _Float16* qb16  = ql16  + (size_t)6291456;  // 12,582,912
  _Float16* kvf16 = qb16  + (size_t)12582912; // 2,359,296
  _Float16* kvn16 = kvf16 + (size_t)2359296;  // 2,097,152
  _Float16* fcc16 = kvn16 + (size_t)2097152;  // 65,536
  _Float16* fcp16 = fcc16 + (size_t)65536;    // 65,536
  // aliases
  _Float16* x216  = q16;
  _Float16* keff  = key16;
  _Float16* W1c   = wqa16;
  _Float16* W2c   = W1c + (size_t)1048576;
  _Float16* Cpe16 = wqb16;
  _Float16* C2h   = Cpe16 + (size_t)T_ * C_;
  _Float16* P2h   = C2h + (size_t)T_ * 128;
  _Float16* pkv16 = wkva16;
  _Float16* vT    = ql16;
  float*    qlp   = out;  // d_out as fp32 scratch (dead after LN)

  // 0. all f32->f16 conversions in one kernel
  conv_all<<<14720, 256, 0, stream>>>(query, key, wq_a, wq_b, wkv_a, wo, fc_c_w, fc_p_w,
                                      q16, key16, wqa16, wqb16, wkva16, wo16, fcc16, fcp16);
  // 1. qlp = query @ wq_a^T (fp32 out in d_out)
  gemm16<false,false,false,false><<<dim3(QR_/128, M/128), 256, 0, stream>>>(
      q16, wqa16, nullptr, qlp, nullptr, QR_, E_, E_, E_, QR_, 0,0,0,0,0,0);
  // (wqa16 dead -> W1c/W2c)
  conv_wkvb<<<8192, 256, 0, stream>>>(wkvb, W1c, W2c);
  // 2. LN -> ql16
  ln_rows<float,true><<<M, 256, 0, stream>>>(qlp, nullptr, ql16, q_ln_g, q_ln_b,
                                             QR_, QR_, QR_);
  // 3. qb16 = ql16 @ wq_b^T
  gemm16<true,false,false,false><<<dim3(3072/128, M/128), 256, 0, stream>>>(
      ql16, wqb16, nullptr, nullptr, qb16, 3072, QR_, QR_, QR_, 3072, 0,0,0,0,0,0);
  // 4. rope q_pe in place
  rope_q16<<<M * H_, 64, 0, stream>>>(qb16, ps);
  // 5. kvf16 = key @ wkv_a^T (N=576; B-overreads stay inside d_ws)
  gemm16<true,true,false,false><<<dim3(5, M/128), 256, 0, stream>>>(
      key16, wkva16, nullptr, nullptr, kvf16, 576, E_, E_, E_, 576, 0,0,0,0,0,0);
  // 6. kvn16 = LN(kvf16[:, :512])
  ln_rows<_Float16,true><<<M, 256, 0, stream>>>(kvf16, nullptr, kvn16, kv_ln_g, kv_ln_b,
                                                C_, 576, C_);
  // 7. kpe -> keff[...,128:192] (key16 dead)
  rope_k16<<<dim3(T_, B_), 64, 0, stream>>>(kvf16, keff);
  // 8. PE table f16 (wqb16 dead)
  pe16<<<T_, 256, 0, stream>>>(Cpe16);
  // 9. C2h = Cpe16 @ fcc16^T + fc_c_b
  gemm16<true,false,true,false><<<dim3(1, T_/128), 256, 0, stream>>>(
      Cpe16, fcc16, fc_c_b, nullptr, C2h, 128, C_, C_, C_, 128, 0,0,0,0,0,0);
  // 10. P2h = kvn16 @ fcp16^T + fc_p_b
  gemm16<true,false,true,false><<<dim3(1, M/128), 256, 0, stream>>>(
      kvn16, fcp16, fc_p_b, nullptr, P2h, 128, C_, C_, C_, 128, 0,0,0,0,0,0);
  // 11. gate -> pkv16 (wkva16 dead)
  gate_kernel<<<dim3(T_, B_), 64, 0, stream>>>(C2h, P2h, kvn16, pkv16);
  // 12a. khead: keff[b][h][:, 0:128] = pkv[b] @ W1c[h]^T  (z = b*16+h, ql16 dead)
  gemm16<true,false,false,false><<<dim3(1, T_/128, 32), 256, 0, stream>>>(
      pkv16, W1c, nullptr, nullptr, keff, 128, C_, C_, C_, 192,
      (long)T_*C_, 0L, 0L, (long)128*C_, (long)H_*T_*192, (long)T_*192);
  // 12b. vT[b][h] = (pkv[b] @ W2c[h]^T)^T
  gemm16<true,false,false,true><<<dim3(1, T_/128, 32), 256, 0, stream>>>(
      pkv16, W2c, nullptr, nullptr, vT, 128, C_, C_, C_, T_,
      (long)T_*C_, 0L, 0L, (long)128*C_, (long)H_*128*T_, (long)128*T_);
  // 13. flash attention -> x216 (q16 dead)
  attn_flash<<<dim3(1024), 256, 0, stream>>>(qb16, keff, vT, x216);
  // 14. out = x216 @ wo16^T (fp32 out)
  gemm16<false,false,false,false><<<dim3(E_/128, M/128), 256, 0, stream>>>(
      x216, wo16, nullptr, out, nullptr, E_, E_, E_, E_, E_, 0,0,0,0,0,0);
}

// Round 9
// 379.018 us; speedup vs baseline: 19.7652x; 1.0435x over previous
//
#include <hip/hip_runtime.h>
#include <math.h>

#define S_ 2048
#define B_ 2
#define H_ 16
#define E_ 2048
#define QR_ 1536
#define NOPE_ 128
#define ROPE_ 64
#define C_ 512
#define VH_ 128
#define T_ 1024
#define LN1E4 9.210340371976184f
#define SCALE_ 0.07216878364870323f  // 192^-0.5

typedef _Float16 half8 __attribute__((ext_vector_type(8)));
typedef _Float16 half4 __attribute__((ext_vector_type(4)));
typedef __fp16 fp16x2 __attribute__((ext_vector_type(2)));
typedef float floatx4 __attribute__((ext_vector_type(4)));
#define MFMA16(a, b, c) __builtin_amdgcn_mfma_f32_16x16x32_f16(a, b, c, 0, 0, 0)

__device__ __forceinline__ void gload16(const _Float16* g, _Float16* l) {
  __builtin_amdgcn_global_load_lds(
      (__attribute__((address_space(1))) const void*)g,
      (__attribute__((address_space(3))) void*)l, 16, 0, 0);
}

// bijective XCD-chunked swizzle (m204): contiguous chunks of work per XCD
__device__ __forceinline__ int xcd_swizzle(int orig, int nwg) {
  int q8 = nwg >> 3, r8 = nwg & 7, xcd = orig & 7, base = orig >> 3;
  return (xcd < r8 ? xcd * (q8 + 1) : r8 * (q8 + 1) + (xcd - r8) * q8) + base;
}

// ---------------- fused f32 -> f16 conversion for 8 tensors ----------------
__global__ __launch_bounds__(256) void conv_all(
    const float* __restrict__ q, const float* __restrict__ k,
    const float* __restrict__ wqa, const float* __restrict__ wqb,
    const float* __restrict__ wkva, const float* __restrict__ wo,
    const float* __restrict__ fcc, const float* __restrict__ fcp,
    _Float16* q16, _Float16* k16, _Float16* wqa16, _Float16* wqb16,
    _Float16* wkva16, _Float16* wo16, _Float16* fcc16, _Float16* fcp16)
{
  size_t i = (size_t)blockIdx.x * 256 + threadIdx.x;  // half8-chunk index
  const float* in; _Float16* out; size_t off;
  if      (i < 1048576) { in = q;    out = q16;    off = i; }
  else if (i < 2097152) { in = k;    out = k16;    off = i - 1048576; }
  else if (i < 2490368) { in = wqa;  out = wqa16;  off = i - 2097152; }
  else if (i < 3080192) { in = wqb;  out = wqb16;  off = i - 2490368; }
  else if (i < 3227648) { in = wkva; out = wkva16; off = i - 3080192; }
  else if (i < 3751936) { in = wo;   out = wo16;   off = i - 3227648; }
  else if (i < 3760128) { in = fcc;  out = fcc16;  off = i - 3751936; }
  else                  { in = fcp;  out = fcp16;  off = i - 3760128; }
  float4 a = ((const float4*)in)[2 * off];
  float4 b = ((const float4*)in)[2 * off + 1];
  half8 h = {(_Float16)a.x, (_Float16)a.y, (_Float16)a.z, (_Float16)a.w,
             (_Float16)b.x, (_Float16)b.y, (_Float16)b.z, (_Float16)b.w};
  *(half8*)(out + 8 * off) = h;
}

// ------- f16 MFMA GEMM: global_load_lds + XOR swizzle + DOUBLE-BUFFER counted vmcnt -------
template<bool OUT16, bool NB, bool BIAS, bool TRANSC>
__global__ __launch_bounds__(256) void gemm16(
    const _Float16* __restrict__ A, const _Float16* __restrict__ Bm,
    const float* __restrict__ bias, float* __restrict__ Cf,
    _Float16* __restrict__ Ch, int N, int K, int lda, int ldb, int ldc,
    long sAb, long sAh, long sBb, long sBh, long sCb, long sCh)
{
  __shared__ __align__(16) _Float16 Asl[2][128 * 64];
  __shared__ __align__(16) _Float16 Bsl[2][128 * 64];
  const int z = blockIdx.z, zb = z >> 4, zh = z & 15;
  A  += (size_t)zb * sAb + (size_t)zh * sAh;
  Bm += (size_t)zb * sBb + (size_t)zh * sBh;
  if (OUT16) Ch += (size_t)zb * sCb + (size_t)zh * sCh;
  else       Cf += (size_t)zb * sCb + (size_t)zh * sCh;
  const int gx = gridDim.x;
  const int nwg = gx * gridDim.y;
  const int f = xcd_swizzle(blockIdx.y * gx + blockIdx.x, nwg);
  const int bm = (f / gx) * 128, bn = (f % gx) * 128;
  const int tid = threadIdx.x;
  const int w = tid >> 6, lane = tid & 63, l15 = lane & 15, g = lane >> 4;
  const int wm = (w >> 1) * 64, wn = (w & 1) * 64;
  const int srow = w * 32 + (lane >> 3);
  const int sch  = (lane & 7) ^ (lane >> 3);   // inverse-swizzled global chunk
  floatx4 acc[4][4];
  #pragma unroll
  for (int i = 0; i < 4; ++i)
    #pragma unroll
    for (int j = 0; j < 4; ++j) acc[i][j] = (floatx4){0.f, 0.f, 0.f, 0.f};

  auto STAGE = [&](int buf, int k0) {
    _Float16* al = &Asl[buf][w * 2048];
    _Float16* bl = &Bsl[buf][w * 2048];
    #pragma unroll
    for (int i = 0; i < 4; ++i)
      gload16(A + (size_t)(bm + srow + i * 8) * lda + k0 + sch * 8, al + i * 512);
    #pragma unroll
    for (int i = 0; i < 4; ++i)
      gload16(Bm + (size_t)(bn + srow + i * 8) * ldb + k0 + sch * 8, bl + i * 512);
  };

  STAGE(0, 0);
  int cur = 0;
  const int nIter = K >> 6;
  for (int it = 0; it < nIter; ++it) {
    const bool pf = (it + 1 < nIter);
    if (pf) STAGE(cur ^ 1, (it + 1) << 6);      // 8 more in flight (16 total)
    if (pf) asm volatile("s_waitcnt vmcnt(8)" ::: "memory");   // wait cur's 8
    else    asm volatile("s_waitcnt vmcnt(0)" ::: "memory");
    __builtin_amdgcn_sched_barrier(0);
    __builtin_amdgcn_s_barrier();               // publish buf[cur]
    __builtin_amdgcn_sched_barrier(0);
    #pragma unroll
    for (int kk = 0; kk < 2; ++kk) {
      half8 af[4], bf[4];
      const int sw = ((kk * 4 + g) ^ (l15 & 7)) * 8;
      #pragma unroll
      for (int i = 0; i < 4; ++i) {
        af[i] = *(const half8*)&Asl[cur][(wm + i * 16 + l15) * 64 + sw];
        bf[i] = *(const half8*)&Bsl[cur][(wn + i * 16 + l15) * 64 + sw];
      }
      #pragma unroll
      for (int i = 0; i < 4; ++i)
        #pragma unroll
        for (int j = 0; j < 4; ++j)
          acc[i][j] = MFMA16(af[i], bf[j], acc[i][j]);
    }
    asm volatile("s_waitcnt lgkmcnt(0)" ::: "memory");
    __builtin_amdgcn_sched_barrier(0);
    __builtin_amdgcn_s_barrier();               // all reads of buf[cur] done
    __builtin_amdgcn_sched_barrier(0);
    cur ^= 1;
  }

  if (TRANSC) {
    #pragma unroll
    for (int i = 0; i < 4; ++i)
      #pragma unroll
      for (int j = 0; j < 4; ++j) {
        int row = bm + wm + i * 16 + g * 4;
        int col = bn + wn + j * 16 + l15;
        half4 v = {(_Float16)acc[i][j][0], (_Float16)acc[i][j][1],
                   (_Float16)acc[i][j][2], (_Float16)acc[i][j][3]};
        *(half4*)(Ch + (size_t)col * ldc + row) = v;
      }
  } else {
    #pragma unroll
    for (int i = 0; i < 4; ++i)
      #pragma unroll
      for (int j = 0; j < 4; ++j)
        #pragma unroll
        for (int r = 0; r < 4; ++r) {
          int row = bm + wm + i * 16 + g * 4 + r;
          int col = bn + wn + j * 16 + l15;
          if (!NB || col < N) {
            float v = acc[i][j][r];
            if (BIAS) v += bias[col];
            if (OUT16) Ch[(size_t)row * ldc + col] = (_Float16)v;
            else       Cf[(size_t)row * ldc + col] = v;
          }
        }
  }
}

// ---------------- row LayerNorm (templated in/out) ----------------
template<typename TIN, bool OUT16>
__global__ __launch_bounds__(256) void ln_rows(
    const TIN* __restrict__ in, float* __restrict__ outf, _Float16* __restrict__ outh,
    const float* __restrict__ g, const float* __restrict__ bb,
    int L, int ldin, int ldout)
{
  const int row = blockIdx.x;
  const TIN* x = in + (size_t)row * ldin;
  float s = 0.f, s2 = 0.f;
  for (int i = threadIdx.x; i < L; i += 256) {
    float v = (float)x[i]; s += v; s2 += v * v;
  }
  #pragma unroll
  for (int off = 32; off; off >>= 1) {
    s  += __shfl_xor(s, off, 64);
    s2 += __shfl_xor(s2, off, 64);
  }
  __shared__ float rs[4], rs2[4];
  int lane = threadIdx.x & 63, w = threadIdx.x >> 6;
  if (lane == 0) { rs[w] = s; rs2[w] = s2; }
  __syncthreads();
  s  = rs[0] + rs[1] + rs[2] + rs[3];
  s2 = rs2[0] + rs2[1] + rs2[2] + rs2[3];
  float mean = s / L;
  float var = s2 / L - mean * mean;
  float inv = rsqrtf(var + 1e-5f);
  for (int i = threadIdx.x; i < L; i += 256) {
    float v = ((float)x[i] - mean) * inv * g[i] + bb[i];
    if (OUT16) outh[(size_t)row * ldout + i] = (_Float16)v;
    else       outf[(size_t)row * ldout + i] = v;
  }
}

// ------- rope + normalize q_pe in place (f16), fold ps*scale -------
__global__ __launch_bounds__(64) void rope_q16(_Float16* __restrict__ qb,
                                               const float* __restrict__ ps_ptr)
{
  const int idx = blockIdx.x;
  const int h = idx & (H_ - 1);
  const int row = idx >> 4;
  const int s = row & (S_ - 1);
  _Float16* p = qb + (size_t)row * 3072 + h * 192 + NOPE_;
  const int j = threadIdx.x;
  float o1 = 0.f, o2 = 0.f;
  if (j < 32) {
    float invf = expf(-(float)j * (LN1E4 / 32.f));
    float ang = (float)(S_ - 1 + s) * invf;
    float sn, cs; sincosf(ang, &sn, &cs);
    float x1 = (float)p[2 * j], x2 = (float)p[2 * j + 1];
    o1 = x1 * cs - x2 * sn;
    o2 = x1 * sn + x2 * cs;
  }
  float ss = o1 * o1 + o2 * o2;
  #pragma unroll
  for (int off = 32; off; off >>= 1) ss += __shfl_xor(ss, off, 64);
  float inv = ps_ptr[0] * SCALE_ / fmaxf(sqrtf(ss), 1e-12f);
  if (j < 32) {
    p[2 * j]     = (_Float16)(o1 * inv);
    p[2 * j + 1] = (_Float16)(o2 * inv);
  }
}

// ------- rope + normalize k_pe (odd rows) -> keff[b][h][t][128..192] all h -------
__global__ __launch_bounds__(64) void rope_k16(
    const _Float16* __restrict__ kvf16, _Float16* __restrict__ keff)
{
  const int t = blockIdx.x, b = blockIdx.y;
  const int srow = 2 * t + 1;
  const _Float16* p = kvf16 + ((size_t)(b * S_ + srow)) * 576 + C_;
  const int j = threadIdx.x;
  float o1 = 0.f, o2 = 0.f;
  if (j < 32) {
    float invf = expf(-(float)j * (LN1E4 / 32.f));
    float ang = (float)(S_ - 1 + srow) * invf;
    float sn, cs; sincosf(ang, &sn, &cs);
    float x1 = (float)p[2 * j], x2 = (float)p[2 * j + 1];
    o1 = x1 * cs - x2 * sn;
    o2 = x1 * sn + x2 * cs;
  }
  float ss = o1 * o1 + o2 * o2;
  #pragma unroll
  for (int off = 32; off; off >>= 1) ss += __shfl_xor(ss, off, 64);
  float nrm = fmaxf(sqrtf(ss), 1e-12f);
  if (j < 32) {
    _Float16 h1 = (_Float16)(o1 / nrm), h2 = (_Float16)(o2 / nrm);
    #pragma unroll
    for (int h = 0; h < H_; ++h) {
      _Float16* o = keff + ((size_t)((b * H_ + h) * T_) + t) * 192 + NOPE_;
      o[2 * j] = h1; o[2 * j + 1] = h2;
    }
  }
}

// ---------------- sinusoidal PE table (f16) ----------------
__global__ __launch_bounds__(256) void pe16(_Float16* __restrict__ Cpe16)
{
  const int t = blockIdx.x;
  const int i = threadIdx.x;
  float dv = expf(-(float)(2 * i) * (LN1E4 / 512.f));
  float ang = (float)t * dv;
  float sn, cs; sincosf(ang, &sn, &cs);
  Cpe16[(size_t)t * C_ + 2 * i]     = (_Float16)sn;
  Cpe16[(size_t)t * C_ + 2 * i + 1] = (_Float16)cs;
}

// ---------------- gate: pkv16[b][t] = w0*kvn[2t] + w1*kvn[2t+1] (all f16 in) ----------------
__global__ __launch_bounds__(64) void gate_kernel(
    const _Float16* __restrict__ C2, const _Float16* __restrict__ P2,
    const _Float16* __restrict__ kvn16, _Float16* __restrict__ pkv16)
{
  const int t = blockIdx.x, b = blockIdx.y;
  const int j = threadIdx.x;
  const _Float16* c2 = C2 + (size_t)t * 128;
  const _Float16* p0 = P2 + ((size_t)(b * S_ + 2 * t)) * 128;
  const _Float16* p1 = p0 + 128;
  float d0 = (float)c2[j] * (float)p0[j] + (float)c2[j + 64] * (float)p0[j + 64];
  float d1 = (float)c2[j] * (float)p1[j] + (float)c2[j + 64] * (float)p1[j + 64];
  #pragma unroll
  for (int off = 32; off; off >>= 1) {
    d0 += __shfl_xor(d0, off, 64);
    d1 += __shfl_xor(d1, off, 64);
  }
  float w0 = 1.f / (1.f + expf(-d0));
  float w1 = 1.f / (1.f + expf(-d1));
  const _Float16* k0 = kvn16 + ((size_t)(b * S_ + 2 * t)) * C_;
  const _Float16* k1 = k0 + C_;
  _Float16* o = pkv16 + ((size_t)(b * T_ + t)) * C_;
  #pragma unroll
  for (int it = 0; it < 2; ++it) {
    int c = j * 4 + it * 256;
    #pragma unroll
    for (int u = 0; u < 4; ++u)
      o[c + u] = (_Float16)(w0 * (float)k0[c + u] + w1 * (float)k1[c + u]);
  }
}

// ---- conv_wkvb: W1c[h][d][c] = wkvb[h][d][c]*SCALE (f16); W2c = wkvb[h][128+d][c] ----
__global__ __launch_bounds__(256) void conv_wkvb(
    const float* __restrict__ wkvb, _Float16* __restrict__ W1c,
    _Float16* __restrict__ W2c)
{
  int i = blockIdx.x * 256 + threadIdx.x;
  const int half = 16 * 128 * 512;
  if (i < half) {
    int c = i & 511, d = (i >> 9) & 127, h = i >> 16;
    W1c[i] = (_Float16)(wkvb[((size_t)(h * 256 + d)) * 512 + c] * SCALE_);
  } else {
    int j = i - half;
    int c = j & 511, d = (j >> 9) & 127, h = j >> 16;
    W2c[j] = (_Float16)wkvb[((size_t)(h * 256 + 128 + d)) * 512 + c];
  }
}

// ------- flash attention, swapped-QK^T register softmax (no P_lds) -------
// grid = 1024 flat blocks (XCD-chunk-swizzled), 4 waves x 16 q-rows, 3 blocks/CU.
__global__ __launch_bounds__(256, 3) void attn_flash(
    const _Float16* __restrict__ qb16, const _Float16* __restrict__ keff,
    const _Float16* __restrict__ vT, _Float16* __restrict__ x216)
{
  __shared__ __align__(16) _Float16 K_lds[64 * 200];  // 25.6 KB
  __shared__ __align__(16) _Float16 V_lds[128 * 72];  // 18.4 KB
  const int f = xcd_swizzle(blockIdx.x, 1024);
  const int st = f & 31, h = (f >> 5) & 15, b = f >> 9;
  const int tid = threadIdx.x, w = tid >> 6, lane = tid & 63;
  const int l15 = lane & 15, g = lane >> 4;
  const int rq = b * S_ + st * 64 + w * 16;
  const _Float16* qrow = qb16 + (size_t)(rq + l15) * 3072 + h * 192;
  half8 qB[6];   // B-fragment: lane holds q-row = l15, k-chunk kk*32+g*8
  #pragma unroll
  for (int kk = 0; kk < 6; ++kk) qB[kk] = *(const half8*)(qrow + kk * 32 + g * 8);
  floatx4 O[8];  // O[cc][r] = O[q = g*4+r][d = cc*16+l15]
  #pragma unroll
  for (int i = 0; i < 8; ++i) O[i] = (floatx4){0.f, 0.f, 0.f, 0.f};
  float m = -3e38f, l = 0.f;   // per-lane softmax state for q = l15
  const _Float16* kb = keff + (size_t)(b * H_ + h) * T_ * 192;
  const _Float16* vb = vT   + (size_t)(b * H_ + h) * 128 * T_;

  const int krow[6] = {(tid) / 24, (tid + 256) / 24, (tid + 512) / 24,
                       (tid + 768) / 24, (tid + 1024) / 24, (tid + 1280) / 24};
  const int kcol[6] = {(tid % 24) * 8, ((tid + 256) % 24) * 8, ((tid + 512) % 24) * 8,
                       ((tid + 768) % 24) * 8, ((tid + 1024) % 24) * 8, ((tid + 1280) % 24) * 8};
  half8 kreg[6], vreg[4];

  #pragma unroll
  for (int p = 0; p < 6; ++p)
    kreg[p] = *(const half8*)(kb + (size_t)krow[p] * 192 + kcol[p]);
  #pragma unroll
  for (int p = 0; p < 4; ++p) {
    int c = tid + p * 256;
    vreg[p] = *(const half8*)(vb + (size_t)(c >> 3) * T_ + (c & 7) * 8);
  }
  #pragma unroll
  for (int p = 0; p < 6; ++p)
    *(half8*)&K_lds[krow[p] * 200 + kcol[p]] = kreg[p];
  #pragma unroll
  for (int p = 0; p < 4; ++p) {
    int c = tid + p * 256;
    *(half8*)&V_lds[(c >> 3) * 72 + (c & 7) * 8] = vreg[p];
  }
  __syncthreads();

  const int srcA = l15 + ((g & 1) << 5);  // lane of group 2*(g&1)
  const int srcB = srcA + 16;             // lane of group 2*(g&1)+1
  const bool hi = (g >> 1) != 0;

  for (int kt = 0; kt < 16; ++kt) {
    if (kt < 15) {
      const int t1 = (kt + 1) * 64;
      #pragma unroll
      for (int p = 0; p < 6; ++p)
        kreg[p] = *(const half8*)(kb + (size_t)(t1 + krow[p]) * 192 + kcol[p]);
      #pragma unroll
      for (int p = 0; p < 4; ++p) {
        int c = tid + p * 256;
        vreg[p] = *(const half8*)(vb + (size_t)(c >> 3) * T_ + t1 + (c & 7) * 8);
      }
    }
    // swapped scores: sc[ct][r] = S[t = ct*16+g*4+r][q = l15]
    floatx4 sc[4];
    #pragma unroll
    for (int i = 0; i < 4; ++i) sc[i] = (floatx4){0.f, 0.f, 0.f, 0.f};
    __builtin_amdgcn_s_setprio(1);
    #pragma unroll
    for (int kk = 0; kk < 6; ++kk)
      #pragma unroll
      for (int ct = 0; ct < 4; ++ct)
        sc[ct] = MFMA16(
            *(const half8*)&K_lds[(ct * 16 + l15) * 200 + kk * 32 + g * 8],
            qB[kk], sc[ct]);
    __builtin_amdgcn_s_setprio(0);
    // per-lane (q = l15) online softmax; cross-group reduce = 2 shfls
    float pm = sc[0][0];
    #pragma unroll
    for (int ct = 0; ct < 4; ++ct)
      #pragma unroll
      for (int r = 0; r < 4; ++r) pm = fmaxf(pm, sc[ct][r]);
    pm = fmaxf(pm, __shfl_xor(pm, 16, 64));
    pm = fmaxf(pm, __shfl_xor(pm, 32, 64));
    int ok = pm <= m + 8.f;
    if (!__all(ok)) {
      float mn = fmaxf(m, pm);
      float sf = __expf(m - mn);
      m = mn; l *= sf;
      float sfO[4];
      #pragma unroll
      for (int r = 0; r < 4; ++r) sfO[r] = __shfl(sf, g * 4 + r, 64);
      #pragma unroll
      for (int cc = 0; cc < 8; ++cc) {
        O[cc][0] *= sfO[0]; O[cc][1] *= sfO[1];
        O[cc][2] *= sfO[2]; O[cc][3] *= sfO[3];
      }
    }
    float rs = 0.f;
    #pragma unroll
    for (int ct = 0; ct < 4; ++ct)
      #pragma unroll
      for (int r = 0; r < 4; ++r) {
        float e = __expf(sc[ct][r] - m);
        sc[ct][r] = e; rs += e;
      }
    rs += __shfl_xor(rs, 16, 64);
    rs += __shfl_xor(rs, 32, 64);
    l += rs;
    // pack P to f16 pairs: pk[ct][j] = (P[t=ct*16+g*4+2j], P[t+1]) for q=l15
    unsigned pk[4][2];
    #pragma unroll
    for (int ct = 0; ct < 4; ++ct) {
      union { fp16x2 h; unsigned u; } c0, c1;
      c0.h = __builtin_amdgcn_cvt_pkrtz(sc[ct][0], sc[ct][1]);
      c1.h = __builtin_amdgcn_cvt_pkrtz(sc[ct][2], sc[ct][3]);
      pk[ct][0] = c0.u; pk[ct][1] = c1.u;
    }
    // PV: assemble PA fragment (lane: row q=l15, k = t = kc*32+g*8..+7) via shfl
    __builtin_amdgcn_s_setprio(1);
    #pragma unroll
    for (int kc = 0; kc < 2; ++kc) {
      unsigned a0 = __shfl((int)pk[2 * kc][0], srcA, 64);
      unsigned b0 = __shfl((int)pk[2 * kc + 1][0], srcA, 64);
      unsigned a1 = __shfl((int)pk[2 * kc][1], srcA, 64);
      unsigned b1 = __shfl((int)pk[2 * kc + 1][1], srcA, 64);
      unsigned a2 = __shfl((int)pk[2 * kc][0], srcB, 64);
      unsigned b2 = __shfl((int)pk[2 * kc + 1][0], srcB, 64);
      unsigned a3 = __shfl((int)pk[2 * kc][1], srcB, 64);
      unsigned b3 = __shfl((int)pk[2 * kc + 1][1], srcB, 64);
      union { unsigned u[4]; half8 h; } pa;
      pa.u[0] = hi ? b0 : a0;
      pa.u[1] = hi ? b1 : a1;
      pa.u[2] = hi ? b2 : a2;
      pa.u[3] = hi ? b3 : a3;
      #pragma unroll
      for (int cc = 0; cc < 8; ++cc)
        O[cc] = MFMA16(pa.h,
            *(const half8*)&V_lds[(cc * 16 + l15) * 72 + kc * 32 + g * 8], O[cc]);
    }
    __builtin_amdgcn_s_setprio(0);
    if (kt < 15) {
      __syncthreads();
      #pragma unroll
      for (int p = 0; p < 6; ++p)
        *(half8*)&K_lds[krow[p] * 200 + kcol[p]] = kreg[p];
      #pragma unroll
      for (int p = 0; p < 4; ++p) {
        int c = tid + p * 256;
        *(half8*)&V_lds[(c >> 3) * 72 + (c & 7) * 8] = vreg[p];
      }
      __syncthreads();
    }
  }
  float il = 1.f / l;
  float ilO[4];
  #pragma unroll
  for (int r = 0; r < 4; ++r) ilO[r] = __shfl(il, g * 4 + r, 64);
  #pragma unroll
  for (int cc = 0; cc < 8; ++cc)
    #pragma unroll
    for (int r = 0; r < 4; ++r)
      x216[(size_t)(rq + g * 4 + r) * 2048 + h * 128 + cc * 16 + l15] =
          (_Float16)(O[cc][r] * ilO[r]);
}

extern "C" void kernel_launch(void* const* d_in, const int* in_sizes, int n_in,
                              void* d_out, int out_size, void* d_ws, size_t ws_size,
                              hipStream_t stream)
{
  (void)in_sizes; (void)n_in; (void)out_size; (void)ws_size;
  const float* query  = (const float*)d_in[0];
  const float* key    = (const float*)d_in[1];
  const float* wq_a   = (const float*)d_in[3];
  const float* q_ln_g = (const float*)d_in[4];
  const float* q_ln_b = (const float*)d_in[5];
  const float* wq_b   = (const float*)d_in[6];
  const float* wkv_a  = (const float*)d_in[7];
  const float* kv_ln_g= (const float*)d_in[8];
  const float* kv_ln_b= (const float*)d_in[9];
  const float* wkvb   = (const float*)d_in[10];
  const float* wo     = (const float*)d_in[11];
  const float* fc_c_w = (const float*)d_in[12];
  const float* fc_c_b = (const float*)d_in[13];
  const float* fc_p_w = (const float*)d_in[14];
  const float* fc_p_b = (const float*)d_in[15];
  const float* ps     = (const float*)d_in[16];
  float* out = (float*)d_out;

  const int M = B_ * S_; // 4096
  // ---- workspace layout (halves), ~108 MB, heavy aliasing ----
  _Float16* hws   = (_Float16*)d_ws;
  _Float16* q16   = hws;                      // 8,388,608   (later: x216)
  _Float16* key16 = q16   + (size_t)8388608;  // 8,388,608   (later: keff 6,291,456)
  _Float16* wqa16 = key16 + (size_t)8388608;  // 3,145,728   (later: W1c|W2c 2,097,152)
  _Float16* wqb16 = wqa16 + (size_t)3145728;  // 4,718,592   (later: Cpe16/C2h/P2h)
  _Float16* wkva16= wqb16 + (size_t)4718592;  // 1,179,648   (later: pkv16 1,048,576)
  _Float16* wo16  = wkva16+ (size_t)1179648;  // 4,194,304
  _Float16* ql16  = wo16  + (size_t)4194304;  // 6,291,456   (later: vT 4,194,304)
  _Float16* qb16  = ql16  + (size_t)6291456;  // 12,582,912
  _Float16* kvf16 = qb16  + (size_t)12582912; // 2,359,296
  _Float16* kvn16 = kvf16 + (size_t)2359296;  // 2,097,152
  _Float16* fcc16 = kvn16 + (size_t)2097152;  // 65,536
  _Float16* fcp16 = fcc16 + (size_t)65536;    // 65,536
  // aliases
  _Float16* x216  = q16;
  _Float16* keff  = key16;
  _Float16* W1c   = wqa16;
  _Float16* W2c   = W1c + (size_t)1048576;
  _Float16* Cpe16 = wqb16;
  _Float16* C2h   = Cpe16 + (size_t)T_ * C_;
  _Float16* P2h   = C2h + (size_t)T_ * 128;
  _Float16* pkv16 = wkva16;
  _Float16* vT    = ql16;
  float*    qlp   = out;  // d_out as fp32 scratch (dead after LN)

  // 0. all f32->f16 conversions in one kernel
  conv_all<<<14720, 256, 0, stream>>>(query, key, wq_a, wq_b, wkv_a, wo, fc_c_w, fc_p_w,
                                      q16, key16, wqa16, wqb16, wkva16, wo16, fcc16, fcp16);
  // 1. qlp = query @ wq_a^T (fp32 out in d_out)
  gemm16<false,false,false,false><<<dim3(QR_/128, M/128), 256, 0, stream>>>(
      q16, wqa16, nullptr, qlp, nullptr, QR_, E_, E_, E_, QR_, 0,0,0,0,0,0);
  // (wqa16 dead -> W1c/W2c)
  conv_wkvb<<<8192, 256, 0, stream>>>(wkvb, W1c, W2c);
  // 2. LN -> ql16
  ln_rows<float,true><<<M, 256, 0, stream>>>(qlp, nullptr, ql16, q_ln_g, q_ln_b,
                                             QR_, QR_, QR_);
  // 3. qb16 = ql16 @ wq_b^T
  gemm16<true,false,false,false><<<dim3(3072/128, M/128), 256, 0, stream>>>(
      ql16, wqb16, nullptr, nullptr, qb16, 3072, QR_, QR_, QR_, 3072, 0,0,0,0,0,0);
  // 4. rope q_pe in place
  rope_q16<<<M * H_, 64, 0, stream>>>(qb16, ps);
  // 5. kvf16 = key @ wkv_a^T (N=576; B-overreads stay inside d_ws)
  gemm16<true,true,false,false><<<dim3(5, M/128), 256, 0, stream>>>(
      key16, wkva16, nullptr, nullptr, kvf16, 576, E_, E_, E_, 576, 0,0,0,0,0,0);
  // 6. kvn16 = LN(kvf16[:, :512])
  ln_rows<_Float16,true><<<M, 256, 0, stream>>>(kvf16, nullptr, kvn16, kv_ln_g, kv_ln_b,
                                                C_, 576, C_);
  // 7. kpe -> keff[...,128:192] (key16 dead)
  rope_k16<<<dim3(T_, B_), 64, 0, stream>>>(kvf16, keff);
  // 8. PE table f16 (wqb16 dead)
  pe16<<<T_, 256, 0, stream>>>(Cpe16);
  // 9. C2h = Cpe16 @ fcc16^T + fc_c_b
  gemm16<true,false,true,false><<<dim3(1, T_/128), 256, 0, stream>>>(
      Cpe16, fcc16, fc_c_b, nullptr, C2h, 128, C_, C_, C_, 128, 0,0,0,0,0,0);
  // 10. P2h = kvn16 @ fcp16^T + fc_p_b
  gemm16<true,false,true,false><<<dim3(1, M/128), 256, 0, stream>>>(
      kvn16, fcp16, fc_p_b, nullptr, P2h, 128, C_, C_, C_, 128, 0,0,0,0,0,0);
  // 11. gate -> pkv16 (wkva16 dead)
  gate_kernel<<<dim3(T_, B_), 64, 0, stream>>>(C2h, P2h, kvn16, pkv16);
  // 12a. khead: keff[b][h][:, 0:128] = pkv[b] @ W1c[h]^T  (z = b*16+h, ql16 dead)
  gemm16<true,false,false,false><<<dim3(1, T_/128, 32), 256, 0, stream>>>(
      pkv16, W1c, nullptr, nullptr, keff, 128, C_, C_, C_, 192,
      (long)T_*C_, 0L, 0L, (long)128*C_, (long)H_*T_*192, (long)T_*192);
  // 12b. vT[b][h] = (pkv[b] @ W2c[h]^T)^T
  gemm16<true,false,false,true><<<dim3(1, T_/128, 32), 256, 0, stream>>>(
      pkv16, W2c, nullptr, nullptr, vT, 128, C_, C_, C_, T_,
      (long)T_*C_, 0L, 0L, (long)128*C_, (long)H_*128*T_, (long)128*T_);
  // 13. flash attention (swapped-QK^T register softmax) -> x216 (q16 dead)
  attn_flash<<<dim3(1024), 256, 0, stream>>>(qb16, keff, vT, x216);
  // 14. out = x216 @ wo16^T (fp32 out)
  gemm16<false,false,false,false><<<dim3(E_/128, M/128), 256, 0, stream>>>(
      x216, wo16, nullptr, out, nullptr, E_, E_, E_, E_, E_, 0,0,0,0,0,0);
}